// Round 9
// baseline (1038.661 us; speedup 1.0000x reference)
//
#include <hip/hip_runtime.h>
#include <math.h>

#define DH 128      // HEADS*HID
#define HID_ 32
#define HEADS_ 4
#define EDIM_ 16
#define NG_ 64

__device__ __forceinline__ float lrelu(float v){ return v > 0.f ? v : 0.2f*v; }
__device__ __forceinline__ float elu_(float v){ return v > 0.f ? v : (__expf(v)-1.f); }

// ---------------- CSR build ----------------
__global__ void k_hist(const int* __restrict__ dst, int E, int* __restrict__ counts){
    int e = blockIdx.x*blockDim.x + threadIdx.x;
    if (e < E) atomicAdd(&counts[dst[e]], 1);
}

__global__ void k_scan1(const int* __restrict__ counts, int N, int* __restrict__ rowst, int* __restrict__ bsums){
    __shared__ int s[512];
    int t = threadIdx.x; int i = blockIdx.x*512 + t;
    int v = (i < N) ? counts[i] : 0;
    s[t] = v; __syncthreads();
    for (int off = 1; off < 512; off <<= 1){
        int x = (t >= off) ? s[t-off] : 0;
        __syncthreads();
        s[t] += x;
        __syncthreads();
    }
    if (i < N) rowst[i] = s[t] - v;
    if (t == 511) bsums[blockIdx.x] = s[511];
}

__global__ void k_scan2(int* bsums, int nb){
    if (threadIdx.x == 0 && blockIdx.x == 0){
        int run = 0;
        for (int b = 0; b < nb; b++){ int v = bsums[b]; bsums[b] = run; run += v; }
    }
}

__global__ void k_scan3(int* rowst, const int* __restrict__ bsums, int N, int E){
    int i = blockIdx.x*blockDim.x + threadIdx.x;
    if (i < N) rowst[i] += bsums[i/512];
    if (i == 0) rowst[N] = E;
}

__global__ void k_scatter(const int* __restrict__ src, const int* __restrict__ dst, int E,
                          const int* __restrict__ rowst, int* __restrict__ cursor,
                          int* __restrict__ srcs, int* __restrict__ dsts, int* __restrict__ perm){
    int e = blockIdx.x*blockDim.x + threadIdx.x;
    if (e < E){
        int d = dst[e];
        int p = rowst[d] + atomicAdd(&cursor[d], 1);
        srcs[p] = src[e]; dsts[p] = d; perm[p] = e;
    }
}

// canonicalize order within each segment (sort by original edge id)
__global__ void k_rank(const int* __restrict__ srcs, const int* __restrict__ dsts,
                       const int* __restrict__ perm, const int* __restrict__ rowst, int E,
                       int* __restrict__ srcs2, int* __restrict__ perm2){
    int p = blockIdx.x*blockDim.x + threadIdx.x;
    if (p >= E) return;
    int d = dsts[p];
    int st = rowst[d], en = rowst[d+1];
    int myp = perm[p];
    int rank = 0;
    for (int q = st; q < en; q++)
        rank += (perm[q] < myp) ? 1 : 0;
    srcs2[st + rank] = srcs[p];
    perm2[st + rank] = myp;
}

// a_edge for 3 layers in canonical order + fused ea column partial sums
__global__ __launch_bounds__(256) void k_aedge3(const float* __restrict__ ea, const int* __restrict__ perm2,
                        int E, const float* __restrict__ Ve,
                        float* __restrict__ ae0, float* __restrict__ ae1, float* __restrict__ ae2,
                        float* __restrict__ partials){
    __shared__ float vsm[192];
    __shared__ float wsum[4][16];
    int t = threadIdx.x;
    if (t < 192) vsm[t] = Ve[t];
    __syncthreads();
    int i = blockIdx.x*blockDim.x + t;
    float v[16];
    #pragma unroll
    for (int q = 0; q < 16; q++) v[q] = 0.f;
    if (i < E){
        int e = perm2[i];
        const float4* p = (const float4*)(ea + (size_t)e*EDIM_);
        #pragma unroll
        for (int q = 0; q < 4; q++){ float4 x = p[q]; v[q*4]=x.x; v[q*4+1]=x.y; v[q*4+2]=x.z; v[q*4+3]=x.w; }
        #pragma unroll
        for (int l = 0; l < 3; l++){
            float o[4];
            #pragma unroll
            for (int h = 0; h < 4; h++){
                float s = 0.f;
                #pragma unroll
                for (int k = 0; k < EDIM_; k++) s += v[k]*vsm[l*64 + k*4 + h];
                o[h] = s;
            }
            float* dp = (l==0) ? ae0 : (l==1) ? ae1 : ae2;
            *(float4*)(dp + (size_t)i*4) = float4{o[0],o[1],o[2],o[3]};
        }
    }
    #pragma unroll
    for (int q = 0; q < 16; q++){
        float s = v[q];
        s += __shfl_xor(s, 1);  s += __shfl_xor(s, 2);  s += __shfl_xor(s, 4);
        s += __shfl_xor(s, 8);  s += __shfl_xor(s, 16); s += __shfl_xor(s, 32);
        v[q] = s;
    }
    int lane = t & 63, wv = t >> 6;
    if (lane < 16) wsum[wv][lane] = v[lane];
    __syncthreads();
    if (t < 16)
        partials[(size_t)blockIdx.x*16 + t] = wsum[0][t] + wsum[1][t] + wsum[2][t] + wsum[3][t];
}

// fallback: one layer's a_edge in canonical order
__global__ void k_aedge1(const float* __restrict__ ea, const int* __restrict__ perm2, int E,
                         const float* __restrict__ Ve, int l, float* __restrict__ aout){
    __shared__ float vsm[64];
    if (threadIdx.x < 64) vsm[threadIdx.x] = Ve[l*64 + threadIdx.x];
    __syncthreads();
    int i = blockIdx.x*blockDim.x + threadIdx.x;
    if (i >= E) return;
    int e = perm2[i];
    const float4* p = (const float4*)(ea + (size_t)e*EDIM_);
    float v[16];
    #pragma unroll
    for (int q = 0; q < 4; q++){ float4 x = p[q]; v[q*4]=x.x; v[q*4+1]=x.y; v[q*4+2]=x.z; v[q*4+3]=x.w; }
    float o[4];
    #pragma unroll
    for (int h = 0; h < 4; h++){
        float s = 0.f;
        #pragma unroll
        for (int k = 0; k < EDIM_; k++) s += v[k]*vsm[k*4 + h];
        o[h] = s;
    }
    *(float4*)(aout + (size_t)i*4) = float4{o[0],o[1],o[2],o[3]};
}

__global__ void k_eamean(const float* __restrict__ ea, int E, float* __restrict__ partials){
    int t = threadIdx.x;
    size_t total = (size_t)E*4;
    float4 acc = {0,0,0,0};
    for (size_t i = (size_t)blockIdx.x*blockDim.x + t; i < total; i += (size_t)gridDim.x*blockDim.x){
        float4 v = ((const float4*)ea)[i];
        acc.x += v.x; acc.y += v.y; acc.z += v.z; acc.w += v.w;
    }
    __shared__ float4 sm[256];
    sm[t] = acc; __syncthreads();
    for (int off = 128; off >= 4; off >>= 1){
        if (t < off){
            sm[t].x += sm[t+off].x; sm[t].y += sm[t+off].y;
            sm[t].z += sm[t+off].z; sm[t].w += sm[t+off].w;
        }
        __syncthreads();
    }
    if (t < 4) ((float4*)partials)[(size_t)blockIdx.x*4 + t] = sm[t];
}

__global__ void k_colfin(const float* __restrict__ partials, int nb,
                         const float* __restrict__ Ve, float invE,
                         float* __restrict__ selfae){
    __shared__ float sm[256];
    int t = threadIdx.x;
    int col = t & 15, grp = t >> 4;
    float s = 0.f;
    for (int r = grp; r < nb; r += 16) s += partials[(size_t)r*16 + col];
    sm[grp*16 + col] = s;
    __syncthreads();
    if (t < 16){
        float tot = 0.f;
        #pragma unroll
        for (int g = 0; g < 16; g++) tot += sm[g*16 + t];
        sm[t] = tot;
    }
    __syncthreads();
    if (t < 12){
        int l = t/4, h = t%4; float s2 = 0.f;
        #pragma unroll
        for (int k = 0; k < EDIM_; k++) s2 += sm[k]*invE*Ve[l*64 + k*4 + h];
        selfae[t] = s2;
    }
}

// setup: Ve (192 values) + Wsd (256 values) in one launch
__global__ void k_setup(const float* __restrict__ We0, const float* __restrict__ ae0,
                        const float* __restrict__ We1, const float* __restrict__ ae1,
                        const float* __restrict__ We2, const float* __restrict__ ae2,
                        float* __restrict__ Ve,
                        const float* __restrict__ W3, const float* __restrict__ as3,
                        const float* __restrict__ ad3, float* __restrict__ Wsd){
    int t = threadIdx.x;
    if (t < 192){
        int l = t/64, r = t%64, k = r/4, h = r%4;
        const float* We = (l==0) ? We0 : (l==1) ? We1 : We2;
        const float* ae = (l==0) ? ae0 : (l==1) ? ae1 : ae2;
        float s = 0.f;
        for (int c = 0; c < HID_; c++) s += We[k*DH + h*HID_ + c] * ae[h*HID_ + c];
        Ve[t] = s;
    }
    {
        int k = t >> 3, r = t & 7, h = r & 3;
        const float* att = (r >= 4) ? ad3 : as3;
        float s = 0.f;
        for (int c = 0; c < HID_; c++) s += W3[k*DH + h*HID_ + c]*att[h*HID_ + c];
        Wsd[k*8 + r] = s;
    }
}

// ---------------- GEMM: [N,128]@[128,128], 64 rows/block, 8x4 per-thread tile.
// FBN: input is pre-BN C of previous layer -> apply elu(v*sc+bo) on tile load.
// Epilogue: h store + per-head asrc/adst.
template<int FBN>
__global__ __launch_bounds__(256) void k_gemm128(const float* __restrict__ X, const float* __restrict__ W,
        const float* __restrict__ attS, const float* __restrict__ attD,
        const float* __restrict__ stats, const float* __restrict__ g, const float* __restrict__ be,
        float invN,
        float* __restrict__ h, float* __restrict__ asrc, float* __restrict__ adst, int N){
    __shared__ float xs[64*128];      // 32 KB
    __shared__ float4 Ws[32*32];      // 16 KB (k-chunk 32 x 128 cols)
    __shared__ float scs[128], bos[128];
    int t = threadIdx.x;
    if (FBN){
        if (t < 128){
            float mu = stats[t]*invN;
            float var = stats[128+t]*invN - mu*mu;
            float sc = rsqrtf(var + 1e-5f)*g[t];
            scs[t] = sc; bos[t] = be[t] - mu*sc;
        }
        __syncthreads();
    }
    int nbase = blockIdx.x*64;
    const float4* xg = (const float4*)(X + (size_t)nbase*DH);
    for (int i = t; i < 64*32; i += 256){
        int row = i >> 5;
        float4 v = (nbase + row < N) ? xg[i] : float4{0,0,0,0};
        if (FBN){
            int f = (i & 31)*4;
            v.x = elu_(v.x*scs[f]   + bos[f]);
            v.y = elu_(v.y*scs[f+1] + bos[f+1]);
            v.z = elu_(v.z*scs[f+2] + bos[f+2]);
            v.w = elu_(v.w*scs[f+3] + bos[f+3]);
        }
        ((float4*)xs)[i] = v;
    }
    int rr = t >> 5;          // 8 rowgroups; rows rr + 8*i
    int cg = t & 31;          // col quad
    float4 acc[8];
    #pragma unroll
    for (int i = 0; i < 8; i++) acc[i] = float4{0,0,0,0};
    const float4* Wg = (const float4*)W;
    for (int kc = 0; kc < 128; kc += 32){
        __syncthreads();
        for (int i = t; i < 32*32; i += 256) Ws[i] = Wg[(kc + (i>>5))*32 + (i&31)];
        __syncthreads();
        #pragma unroll
        for (int k4 = 0; k4 < 8; k4++){
            float4 xv[8];
            #pragma unroll
            for (int i = 0; i < 8; i++)
                xv[i] = *(const float4*)&xs[(rr + 8*i)*128 + kc + k4*4];
            #pragma unroll
            for (int j = 0; j < 4; j++){
                float4 w = Ws[(k4*4 + j)*32 + cg];
                #pragma unroll
                for (int i = 0; i < 8; i++){
                    float xj = (j==0) ? xv[i].x : (j==1) ? xv[i].y : (j==2) ? xv[i].z : xv[i].w;
                    acc[i].x += xj*w.x; acc[i].y += xj*w.y; acc[i].z += xj*w.z; acc[i].w += xj*w.w;
                }
            }
        }
    }
    int hd = cg >> 3;
    float4 as4 = *(const float4*)(attS + hd*HID_ + (cg&7)*4);
    float4 ad4 = *(const float4*)(attD + hd*HID_ + (cg&7)*4);
    #pragma unroll
    for (int i = 0; i < 8; i++){
        int n = nbase + rr + 8*i;
        float ps = acc[i].x*as4.x + acc[i].y*as4.y + acc[i].z*as4.z + acc[i].w*as4.w;
        float pd = acc[i].x*ad4.x + acc[i].y*ad4.y + acc[i].z*ad4.z + acc[i].w*ad4.w;
        ps += __shfl_xor(ps,1); ps += __shfl_xor(ps,2); ps += __shfl_xor(ps,4);
        pd += __shfl_xor(pd,1); pd += __shfl_xor(pd,2); pd += __shfl_xor(pd,4);
        if (n < N){
            *(float4*)(h + (size_t)n*DH + cg*4) = acc[i];
            if ((cg & 7) == 0){ asrc[n*4 + hd] = ps; adst[n*4 + hd] = pd; }
        }
    }
}

// GAT edge phase, layers 1/2: 4 nodes/wave, 16 lanes/node, serial edges.
// Fused per-block BN stats (sum/sumsq) of the output -> spart.
template<int CONCAT>
__global__ __launch_bounds__(256) void k_aggL(const int* __restrict__ rowst, const int* __restrict__ srcs,
        const float* __restrict__ asrc, const float* __restrict__ adst, const float* __restrict__ aedge,
        const float* __restrict__ h, const float* __restrict__ selfae4,
        const float* __restrict__ bias, float* __restrict__ out, float* __restrict__ spart, int N){
    __shared__ float smC[16][128];
    int t = threadIdx.x;
    int lane = t & 63, wv = t >> 6;
    int grp = lane >> 4;
    int fl  = lane & 15;
    int hd  = fl >> 2;
    int f   = fl*8;
    int node = wv*4 + grp;
    int n = blockIdx.x*16 + node;
    bool active = n < N;
    int st = 0, en = 0;
    float dvh = 0.f;
    if (active){
        st = rowst[n]; en = rowst[n+1];
        dvh = adst[(size_t)n*4 + hd];
    }
    float4 acc0 = {0,0,0,0}, acc1 = {0,0,0,0};
    float dsum = 0.f;
    for (int i = st; i < en; i++){
        int s = srcs[i];
        float w = __expf(lrelu(asrc[(size_t)s*4 + hd] + dvh + aedge[(size_t)i*4 + hd]));
        dsum += w;
        const float4* hp = (const float4*)(h + (size_t)s*DH + f);
        float4 a = hp[0], b4 = hp[1];
        acc0.x += w*a.x;  acc0.y += w*a.y;  acc0.z += w*a.z;  acc0.w += w*a.w;
        acc1.x += w*b4.x; acc1.y += w*b4.y; acc1.z += w*b4.z; acc1.w += w*b4.w;
    }
    if (active){
        float es = __expf(lrelu(asrc[(size_t)n*4 + hd] + dvh + selfae4[hd]));
        float invd = 1.f/(dsum + es + 1e-16f);
        const float4* hnp = (const float4*)(h + (size_t)n*DH + f);
        float4 hnA = hnp[0], hnB = hnp[1];
        acc0.x = (acc0.x + es*hnA.x)*invd; acc0.y = (acc0.y + es*hnA.y)*invd;
        acc0.z = (acc0.z + es*hnA.z)*invd; acc0.w = (acc0.w + es*hnA.w)*invd;
        acc1.x = (acc1.x + es*hnB.x)*invd; acc1.y = (acc1.y + es*hnB.y)*invd;
        acc1.z = (acc1.z + es*hnB.z)*invd; acc1.w = (acc1.w + es*hnB.w)*invd;
    }
    if (CONCAT){
        float4 oA = {0,0,0,0}, oB = {0,0,0,0};
        if (active){
            const float* b4 = bias + f;
            oA = float4{acc0.x + b4[0], acc0.y + b4[1], acc0.z + b4[2], acc0.w + b4[3]};
            oB = float4{acc1.x + b4[4], acc1.y + b4[5], acc1.z + b4[6], acc1.w + b4[7]};
            *(float4*)(out + (size_t)n*DH + f)     = oA;
            *(float4*)(out + (size_t)n*DH + f + 4) = oB;
        }
        *(float4*)&smC[node][f]     = oA;
        *(float4*)&smC[node][f + 4] = oB;
    } else {
        #pragma unroll
        for (int msk = 4; msk <= 8; msk <<= 1){
            acc0.x += __shfl_xor(acc0.x, msk); acc0.y += __shfl_xor(acc0.y, msk);
            acc0.z += __shfl_xor(acc0.z, msk); acc0.w += __shfl_xor(acc0.w, msk);
            acc1.x += __shfl_xor(acc1.x, msk); acc1.y += __shfl_xor(acc1.y, msk);
            acc1.z += __shfl_xor(acc1.z, msk); acc1.w += __shfl_xor(acc1.w, msk);
        }
        if (fl < 4){
            int c = fl*8;
            float4 oA = {0,0,0,0}, oB = {0,0,0,0};
            if (active){
                const float* b4 = bias + c;
                oA = float4{0.25f*acc0.x + b4[0], 0.25f*acc0.y + b4[1],
                            0.25f*acc0.z + b4[2], 0.25f*acc0.w + b4[3]};
                oB = float4{0.25f*acc1.x + b4[4], 0.25f*acc1.y + b4[5],
                            0.25f*acc1.z + b4[6], 0.25f*acc1.w + b4[7]};
                *(float4*)(out + (size_t)n*HID_ + c)     = oA;
                *(float4*)(out + (size_t)n*HID_ + c + 4) = oB;
            }
            *(float4*)&smC[node][c]     = oA;
            *(float4*)&smC[node][c + 4] = oB;
        }
    }
    __syncthreads();
    const int D = CONCAT ? 128 : 32;
    if (t < D){
        float s = 0.f, s2 = 0.f;
        #pragma unroll 4
        for (int r = 0; r < 16; r++){
            float v = smC[r][t];
            s += v; s2 += v*v;
        }
        spart[(size_t)blockIdx.x*2*D + t]     = s;
        spart[(size_t)blockIdx.x*2*D + D + t] = s2;
    }
}

// Layer 3 edge phase: 8 nodes/wave, 8 lanes/node, writes per-head agg[N,128].
__global__ __launch_bounds__(256) void k_aggA(const int* __restrict__ rowst, const int* __restrict__ srcs,
        const float* __restrict__ asrc, const float* __restrict__ adst, const float* __restrict__ aedge,
        const float* __restrict__ A, const float* __restrict__ selfae4,
        float* __restrict__ agg, int N){
    int t = threadIdx.x;
    int lane = t & 63, wv = t >> 6;
    int grp = lane >> 3;
    int fl  = lane & 7;
    int f   = fl*4;
    int n = blockIdx.x*32 + wv*8 + grp;
    bool active = n < N;
    int st = 0, en = 0;
    float4 dv = {0,0,0,0};
    if (active){
        st = rowst[n]; en = rowst[n+1];
        dv = *(const float4*)(adst + (size_t)n*4);
    }
    float4 acc0 = {0,0,0,0}, acc1 = {0,0,0,0}, acc2 = {0,0,0,0}, acc3 = {0,0,0,0};
    float4 dsum = {0,0,0,0};
    for (int i = st; i < en; i++){
        int s = srcs[i];
        float4 av = *(const float4*)(asrc + (size_t)s*4);
        float4 ae4 = *(const float4*)(aedge + (size_t)i*4);
        float w0 = __expf(lrelu(av.x + dv.x + ae4.x));
        float w1 = __expf(lrelu(av.y + dv.y + ae4.y));
        float w2 = __expf(lrelu(av.z + dv.z + ae4.z));
        float w3 = __expf(lrelu(av.w + dv.w + ae4.w));
        dsum.x += w0; dsum.y += w1; dsum.z += w2; dsum.w += w3;
        float4 a = *(const float4*)(A + (size_t)s*HID_ + f);
        acc0.x += w0*a.x; acc0.y += w0*a.y; acc0.z += w0*a.z; acc0.w += w0*a.w;
        acc1.x += w1*a.x; acc1.y += w1*a.y; acc1.z += w1*a.z; acc1.w += w1*a.w;
        acc2.x += w2*a.x; acc2.y += w2*a.y; acc2.z += w2*a.z; acc2.w += w2*a.w;
        acc3.x += w3*a.x; acc3.y += w3*a.y; acc3.z += w3*a.z; acc3.w += w3*a.w;
    }
    if (active){
        float4 av = *(const float4*)(asrc + (size_t)n*4);
        float4 sa = *(const float4*)selfae4;
        float e0 = __expf(lrelu(av.x + dv.x + sa.x));
        float e1 = __expf(lrelu(av.y + dv.y + sa.y));
        float e2 = __expf(lrelu(av.z + dv.z + sa.z));
        float e3 = __expf(lrelu(av.w + dv.w + sa.w));
        float4 aself = *(const float4*)(A + (size_t)n*HID_ + f);
        float i0 = 1.f/(dsum.x + e0 + 1e-16f);
        float i1 = 1.f/(dsum.y + e1 + 1e-16f);
        float i2 = 1.f/(dsum.z + e2 + 1e-16f);
        float i3 = 1.f/(dsum.w + e3 + 1e-16f);
        acc0.x = (acc0.x + e0*aself.x)*i0; acc0.y = (acc0.y + e0*aself.y)*i0;
        acc0.z = (acc0.z + e0*aself.z)*i0; acc0.w = (acc0.w + e0*aself.w)*i0;
        acc1.x = (acc1.x + e1*aself.x)*i1; acc1.y = (acc1.y + e1*aself.y)*i1;
        acc1.z = (acc1.z + e1*aself.z)*i1; acc1.w = (acc1.w + e1*aself.w)*i1;
        acc2.x = (acc2.x + e2*aself.x)*i2; acc2.y = (acc2.y + e2*aself.y)*i2;
        acc2.z = (acc2.z + e2*aself.z)*i2; acc2.w = (acc2.w + e2*aself.w)*i2;
        acc3.x = (acc3.x + e3*aself.x)*i3; acc3.y = (acc3.y + e3*aself.y)*i3;
        acc3.z = (acc3.z + e3*aself.z)*i3; acc3.w = (acc3.w + e3*aself.w)*i3;
        float* ap = agg + (size_t)n*DH;
        *(float4*)(ap +  0 + f) = acc0;
        *(float4*)(ap + 32 + f) = acc1;
        *(float4*)(ap + 64 + f) = acc2;
        *(float4*)(ap + 96 + f) = acc3;
    }
}

// C3 = 0.25*agg@Wmix + b3, 32 rows/block, 1 row x 4 cols per thread.
// Multi-broadcast LDS layout (stride 132), fused BN stats.
__global__ __launch_bounds__(256) void k_w3mix(const float* __restrict__ agg,
        const float* __restrict__ W3, const float* __restrict__ b3,
        float* __restrict__ C, float* __restrict__ spart, int N){
    __shared__ float as_[32*132];     // 16.9 KB, padded stride
    __shared__ float wf[128*32];      // 16 KB: wf[kk*32+c] = W3[k, h*32+c], kk=h*32+k
    __shared__ float ob[32];
    int t = threadIdx.x;
    for (int i = t; i < 4096; i += 256){
        int kk = i >> 5, c = i & 31;
        int hh = kk >> 5, k = kk & 31;
        wf[i] = W3[k*DH + hh*HID_ + c];
    }
    if (t < 32) ob[t] = b3[t];
    int nbase = blockIdx.x*32;
    const float4* ag = (const float4*)(agg + (size_t)nbase*DH);
    for (int i = t; i < 32*32; i += 256){
        int row = i >> 5, col4 = i & 31;
        float4 v = (nbase + row < N) ? ag[i] : float4{0,0,0,0};
        *(float4*)&as_[row*132 + col4*4] = v;
    }
    __syncthreads();
    int rg = t >> 3;     // row 0..31
    int cq = t & 7;      // col quad 0..7
    int n = nbase + rg;
    float4 acc = {0,0,0,0};
    const float* xr = &as_[rg*132];
    const float4* wf4 = (const float4*)wf;
    #pragma unroll 8
    for (int k = 0; k < 128; k++){
        float xv = xr[k];
        float4 w = wf4[k*8 + cq];
        acc.x += xv*w.x; acc.y += xv*w.y; acc.z += xv*w.z; acc.w += xv*w.w;
    }
    float4 o = {0,0,0,0};
    if (n < N){
        o = float4{0.25f*acc.x + ob[cq*4], 0.25f*acc.y + ob[cq*4+1],
                   0.25f*acc.z + ob[cq*4+2], 0.25f*acc.w + ob[cq*4+3]};
        *(float4*)(C + (size_t)n*HID_ + cq*4) = o;
    }
    __syncthreads();
    *(float4*)&as_[rg*132 + cq*4] = o;
    __syncthreads();
    if (t < 32){
        float s = 0.f, s2 = 0.f;
        #pragma unroll 4
        for (int r = 0; r < 32; r++){
            float v = as_[r*132 + t];
            s += v; s2 += v*v;
        }
        spart[(size_t)blockIdx.x*64 + t]      = s;
        spart[(size_t)blockIdx.x*64 + 32 + t] = s2;
    }
}

// asrc/adst for layer 3 from A [N,32]
__global__ void k_attn3(const float* __restrict__ A, int N, const float* __restrict__ Wsd,
                        float* __restrict__ asrc, float* __restrict__ adst){
    __shared__ float ws[256];
    ws[threadIdx.x] = Wsd[threadIdx.x & 255];
    __syncthreads();
    int n = blockIdx.x*blockDim.x + threadIdx.x;
    if (n >= N) return;
    float s[8] = {0,0,0,0,0,0,0,0};
    const float4* ar = (const float4*)(A + (size_t)n*HID_);
    #pragma unroll
    for (int kq = 0; kq < 8; kq++){
        float4 a = ar[kq];
        const float* w0 = &ws[kq*32];
        #pragma unroll
        for (int r = 0; r < 8; r++)
            s[r] += a.x*w0[r] + a.y*w0[8+r] + a.z*w0[16+r] + a.w*w0[24+r];
    }
    *(float4*)(asrc + (size_t)n*4) = float4{s[0],s[1],s[2],s[3]};
    *(float4*)(adst + (size_t)n*4) = float4{s[4],s[5],s[6],s[7]};
}

// reduce per-block BN partials (4-way ILP, deterministic)
__global__ void k_statsred(const float* __restrict__ spart, int nb, int D,
                           float* __restrict__ stats){
    int t = threadIdx.x;
    if (t >= 2*D) return;
    float a0=0.f, a1=0.f, a2=0.f, a3=0.f;
    int b = 0;
    for (; b + 4 <= nb; b += 4){
        a0 += spart[(size_t)b*2*D + t];
        a1 += spart[(size_t)(b+1)*2*D + t];
        a2 += spart[(size_t)(b+2)*2*D + t];
        a3 += spart[(size_t)(b+3)*2*D + t];
    }
    float s = (a0 + a1) + (a2 + a3);
    for (; b < nb; b++) s += spart[(size_t)b*2*D + t];
    stats[t < D ? t : 128 + (t - D)] = s;
}

__global__ void k_bnapply(const float* __restrict__ C, int N, int D,
                          const float* __restrict__ stats, const float* __restrict__ g,
                          const float* __restrict__ b, float* __restrict__ A){
    int idx = blockIdx.x*blockDim.x + threadIdx.x;
    if (idx >= N*D) return;
    int f = idx % D;
    float invN = 1.f/(float)N;
    float mu = stats[f]*invN;
    float var = stats[128 + f]*invN - mu*mu;
    float sc = rsqrtf(var + 1e-5f)*g[f];
    float y = (C[idx] - mu)*sc + b[f];
    A[idx] = elu_(y);
}

// pooling + fc, one block per graph, BN3+elu fused on load
__global__ __launch_bounds__(256) void k_poolfc(const float* __restrict__ C, int N,
        const float* __restrict__ stats, const float* __restrict__ g3, const float* __restrict__ be3,
        float invN,
        const float* __restrict__ gw, const float* __restrict__ gb,
        const int* __restrict__ batch, float* __restrict__ exg,
        const float* __restrict__ fcW, const float* __restrict__ fcb,
        float* __restrict__ out){
    int gId = blockIdx.x;
    int t = threadIdx.x;
    int lo = 0, hi = N;
    while (lo < hi){ int mid = (lo+hi) >> 1; if (batch[mid] < gId) lo = mid+1; else hi = mid; }
    int st = lo;
    hi = N;
    while (lo < hi){ int mid = (lo+hi) >> 1; if (batch[mid] < gId+1) lo = mid+1; else hi = mid; }
    int en = lo;

    __shared__ float gws[32];
    __shared__ float scs[32], bos[32];
    __shared__ float red[256];
    if (t < 32){
        gws[t] = gw[t];
        float mu = stats[t]*invN;
        float var = stats[128+t]*invN - mu*mu;
        float sc = rsqrtf(var + 1e-5f)*g3[t];
        scs[t] = sc; bos[t] = be3[t] - mu*sc;
    }
    __syncthreads();

    float den = 0.f;
    for (int n = st + t; n < en; n += 256){
        const float4* xr = (const float4*)(C + (size_t)n*HID_);
        float s = 0.f;
        #pragma unroll
        for (int q = 0; q < 8; q++){
            float4 v = xr[q];
            int f = q*4;
            s += elu_(v.x*scs[f]   + bos[f])  *gws[f]
               + elu_(v.y*scs[f+1] + bos[f+1])*gws[f+1]
               + elu_(v.z*scs[f+2] + bos[f+2])*gws[f+2]
               + elu_(v.w*scs[f+3] + bos[f+3])*gws[f+3];
        }
        float ex = __expf(s + gb[0]);
        exg[n] = ex;
        den += ex;
    }
    red[t] = den; __syncthreads();
    for (int off = 128; off > 0; off >>= 1){
        if (t < off) red[t] += red[t+off];
        __syncthreads();
    }
    float invd = 1.f/(red[0] + 1e-16f);
    __syncthreads();

    int c = t & 31, rg = t >> 5;
    float acc = 0.f;
    for (int n = st + rg; n < en; n += 8)
        acc += exg[n]*elu_(C[(size_t)n*HID_ + c]*scs[c] + bos[c]);
    red[t] = acc; __syncthreads();
    if (t < 128) red[t] += red[t+128];
    __syncthreads();
    if (t < 64) red[t] += red[t+64];
    __syncthreads();
    if (t < 32) red[t] += red[t+32];
    __syncthreads();
    if (t < 2){
        float s = 0.f;
        for (int cc = 0; cc < 32; cc++) s += red[cc]*invd*fcW[cc*2 + t];
        out[gId*2 + t] = s + fcb[t];
    }
}

extern "C" void kernel_launch(void* const* d_in, const int* in_sizes, int n_in,
                              void* d_out, int out_size, void* d_ws, size_t ws_size,
                              hipStream_t stream){
    const float* x   = (const float*)d_in[0];
    const int*   src = (const int*)d_in[1];
    const int*   dst = (const int*)d_in[2];
    const float* ea  = (const float*)d_in[3];
    const int* batch = (const int*)d_in[4];
    const float *W1=(const float*)d_in[5],  *as1=(const float*)d_in[6],  *ad1=(const float*)d_in[7];
    const float *We1=(const float*)d_in[8], *ae1=(const float*)d_in[9],  *b1=(const float*)d_in[10];
    const float *W2=(const float*)d_in[11], *as2=(const float*)d_in[12], *ad2=(const float*)d_in[13];
    const float *We2=(const float*)d_in[14],*ae2=(const float*)d_in[15], *b2=(const float*)d_in[16];
    const float *W3=(const float*)d_in[17], *as3=(const float*)d_in[18], *ad3=(const float*)d_in[19];
    const float *We3=(const float*)d_in[20],*ae3=(const float*)d_in[21], *b3=(const float*)d_in[22];
    const float *g1=(const float*)d_in[23], *be1=(const float*)d_in[24];
    const float *g2=(const float*)d_in[25], *be2=(const float*)d_in[26];
    const float *g3=(const float*)d_in[27], *be3=(const float*)d_in[28];
    const float *gw=(const float*)d_in[29], *gb=(const float*)d_in[30];
    const float *fcW=(const float*)d_in[31],*fcb=(const float*)d_in[32];
    int N = in_sizes[0]/DH;
    int E = in_sizes[1];
    float invN = 1.f/(float)N;

    const int tb = 256;
    int gE = (E + tb - 1)/tb;
    int nP = (gE > 1024) ? gE : 1024;
    int gL = (N + 15)/16;     // aggL blocks
    int gMix = (N + 31)/32;   // w3mix blocks
    size_t spartN = (size_t)gL*256;    // max partials size (layer1)

    float* ws = (float*)d_ws;
    size_t off = 0;
    float* A = ws + off;    off += (size_t)N*DH;
    float* B = ws + off;    off += (size_t)N*DH;   // h / agg
    float* C = ws + off;    off += (size_t)N*DH;   // pre-BN output
    float* asrc = ws + off; off += (size_t)N*4;
    float* adst = ws + off; off += (size_t)N*4;
    int* ints   = (int*)(ws + off);
    int* srcs   = ints;
    int* dsts   = ints + (size_t)E;
    int* perm   = ints + 2*(size_t)E;
    int* srcs2  = ints + 3*(size_t)E;
    int* perm2  = ints + 4*(size_t)E;
    int* rowst  = ints + 5*(size_t)E;
    int* counts = rowst + (N + 1);
    int* cursor = counts + N;
    int* bsums  = cursor + N;
    off += 5*(size_t)E + (N + 1) + 2*(size_t)N + 256;
    off = (off + 3) & ~(size_t)3;
    float* Ve     = ws + off;      // 192
    float* selfae = Ve + 192;      // 16
    float* stats  = selfae + 16;   // 3*256
    float* Wsd    = stats + 768;   // 256
    float* exg    = Wsd + 256;     // N
    float* partials = exg + N;     // nP*16
    float* spart  = partials + (size_t)nP*16;
    off += 192 + 16 + 768 + 256 + (size_t)N + (size_t)nP*16 + spartN;
    bool full = (off + (size_t)E*12)*sizeof(float) <= ws_size;
    float* ae0 = ws + off;
    float* ae1b = full ? ae0 + (size_t)E*4 : ae0;
    float* ae2b = full ? ae0 + (size_t)E*8 : ae0;

    hipMemsetAsync(counts, 0, (size_t)(2*N + 256)*sizeof(int), stream);

    int nb = (N + 511)/512;
    k_hist<<<gE, tb, 0, stream>>>(dst, E, counts);
    k_scan1<<<nb, 512, 0, stream>>>(counts, N, rowst, bsums);
    k_scan2<<<1, 1, 0, stream>>>(bsums, nb);
    k_scan3<<<(N + tb - 1)/tb, tb, 0, stream>>>(rowst, bsums, N, E);
    k_setup<<<1, 256, 0, stream>>>(We1, ae1, We2, ae2, We3, ae3, Ve, W3, as3, ad3, Wsd);
    k_scatter<<<gE, tb, 0, stream>>>(src, dst, E, rowst, cursor, srcs, dsts, perm);
    k_rank<<<gE, tb, 0, stream>>>(srcs, dsts, perm, rowst, E, srcs2, perm2);
    if (full){
        k_aedge3<<<gE, tb, 0, stream>>>(ea, perm2, E, Ve, ae0, ae1b, ae2b, partials);
        k_colfin<<<1, 256, 0, stream>>>(partials, gE, Ve, 1.f/(float)E, selfae);
    } else {
        k_eamean<<<1024, 256, 0, stream>>>(ea, E, partials);
        k_colfin<<<1, 256, 0, stream>>>(partials, 1024, Ve, 1.f/(float)E, selfae);
    }

    int gG = (N + 63)/64;
    // layer 1 (concat)
    k_gemm128<0><<<gG, 256, 0, stream>>>(x, W1, as1, ad1, stats, g1, be1, invN, B, asrc, adst, N);
    if (!full) k_aedge1<<<gE, tb, 0, stream>>>(ea, perm2, E, Ve, 0, ae0);
    k_aggL<1><<<gL, 256, 0, stream>>>(rowst, srcs2, asrc, adst, ae0, B, selfae + 0, b1, C, spart, N);
    k_statsred<<<1, 256, 0, stream>>>(spart, gL, DH, stats);
    // layer 2 (mean); BN1+elu fused into gemm input
    k_gemm128<1><<<gG, 256, 0, stream>>>(C, W2, as2, ad2, stats, g1, be1, invN, B, asrc, adst, N);
    if (!full) k_aedge1<<<gE, tb, 0, stream>>>(ea, perm2, E, Ve, 1, ae1b);
    k_aggL<0><<<gL, 256, 0, stream>>>(rowst, srcs2, asrc, adst, ae1b, B, selfae + 4, b2, C, spart, N);
    k_statsred<<<1, 256, 0, stream>>>(spart, gL, HID_, stats + 256);
    k_bnapply<<<((size_t)N*HID_ + tb - 1)/tb, tb, 0, stream>>>(C, N, HID_, stats + 256, g2, be2, A);
    // layer 3 (A-space aggregation; W3 as batched GEMM with fused stats)
    k_attn3<<<(N + tb - 1)/tb, tb, 0, stream>>>(A, N, Wsd, asrc, adst);
    if (!full) k_aedge1<<<gE, tb, 0, stream>>>(ea, perm2, E, Ve, 2, ae2b);
    k_aggA<<<(N + 31)/32, 256, 0, stream>>>(rowst, srcs2, asrc, adst, ae2b, A, selfae + 8, B, N);
    k_w3mix<<<gMix, 256, 0, stream>>>(B, W3, b3, C, spart, N);
    k_statsred<<<1, 256, 0, stream>>>(spart, gMix, HID_, stats + 512);
    // pooling + fc (BN3 fused)
    k_poolfc<<<NG_, 256, 0, stream>>>(C, N, stats + 512, g3, be3, invN, gw, gb, batch, exg, fcW, fcb, (float*)d_out);
}

// Round 10
// 549.939 us; speedup vs baseline: 1.8887x; 1.8887x over previous
//
#include <hip/hip_runtime.h>
#include <math.h>

#define DH 128      // HEADS*HID
#define HID_ 32
#define HEADS_ 4
#define EDIM_ 16
#define NG_ 64

__device__ __forceinline__ float lrelu(float v){ return v > 0.f ? v : 0.2f*v; }
__device__ __forceinline__ float elu_(float v){ return v > 0.f ? v : (__expf(v)-1.f); }

// ---------------- CSR build ----------------
__global__ void k_hist(const int* __restrict__ dst, int E, int* __restrict__ counts){
    int e = blockIdx.x*blockDim.x + threadIdx.x;
    if (e < E) atomicAdd(&counts[dst[e]], 1);
}

__global__ void k_scan1(const int* __restrict__ counts, int N, int* __restrict__ rowst, int* __restrict__ bsums){
    __shared__ int s[512];
    int t = threadIdx.x; int i = blockIdx.x*512 + t;
    int v = (i < N) ? counts[i] : 0;
    s[t] = v; __syncthreads();
    for (int off = 1; off < 512; off <<= 1){
        int x = (t >= off) ? s[t-off] : 0;
        __syncthreads();
        s[t] += x;
        __syncthreads();
    }
    if (i < N) rowst[i] = s[t] - v;
    if (t == 511) bsums[blockIdx.x] = s[511];
}

__global__ void k_scan2(int* bsums, int nb){
    if (threadIdx.x == 0 && blockIdx.x == 0){
        int run = 0;
        for (int b = 0; b < nb; b++){ int v = bsums[b]; bsums[b] = run; run += v; }
    }
}

__global__ void k_scan3(int* rowst, const int* __restrict__ bsums, int N, int E){
    int i = blockIdx.x*blockDim.x + threadIdx.x;
    if (i < N) rowst[i] += bsums[i/512];
    if (i == 0) rowst[N] = E;
}

__global__ void k_scatter(const int* __restrict__ src, const int* __restrict__ dst, int E,
                          const int* __restrict__ rowst, int* __restrict__ cursor,
                          int* __restrict__ srcs, int* __restrict__ dsts, int* __restrict__ perm){
    int e = blockIdx.x*blockDim.x + threadIdx.x;
    if (e < E){
        int d = dst[e];
        int p = rowst[d] + atomicAdd(&cursor[d], 1);
        srcs[p] = src[e]; dsts[p] = d; perm[p] = e;
    }
}

// canonicalize order within each segment (sort by original edge id)
__global__ void k_rank(const int* __restrict__ srcs, const int* __restrict__ dsts,
                       const int* __restrict__ perm, const int* __restrict__ rowst, int E,
                       int* __restrict__ srcs2, int* __restrict__ perm2){
    int p = blockIdx.x*blockDim.x + threadIdx.x;
    if (p >= E) return;
    int d = dsts[p];
    int st = rowst[d], en = rowst[d+1];
    int myp = perm[p];
    int rank = 0;
    for (int q = st; q < en; q++)
        rank += (perm[q] < myp) ? 1 : 0;
    srcs2[st + rank] = srcs[p];
    perm2[st + rank] = myp;
}

// a_edge for 3 layers in canonical order + fused ea column partial sums
__global__ __launch_bounds__(256) void k_aedge3(const float* __restrict__ ea, const int* __restrict__ perm2,
                        int E, const float* __restrict__ Ve,
                        float* __restrict__ ae0, float* __restrict__ ae1, float* __restrict__ ae2,
                        float* __restrict__ partials){
    __shared__ float vsm[192];
    __shared__ float wsum[4][16];
    int t = threadIdx.x;
    if (t < 192) vsm[t] = Ve[t];
    __syncthreads();
    int i = blockIdx.x*blockDim.x + t;
    float v[16];
    #pragma unroll
    for (int q = 0; q < 16; q++) v[q] = 0.f;
    if (i < E){
        int e = perm2[i];
        const float4* p = (const float4*)(ea + (size_t)e*EDIM_);
        #pragma unroll
        for (int q = 0; q < 4; q++){ float4 x = p[q]; v[q*4]=x.x; v[q*4+1]=x.y; v[q*4+2]=x.z; v[q*4+3]=x.w; }
        #pragma unroll
        for (int l = 0; l < 3; l++){
            float o[4];
            #pragma unroll
            for (int h = 0; h < 4; h++){
                float s = 0.f;
                #pragma unroll
                for (int k = 0; k < EDIM_; k++) s += v[k]*vsm[l*64 + k*4 + h];
                o[h] = s;
            }
            float* dp = (l==0) ? ae0 : (l==1) ? ae1 : ae2;
            *(float4*)(dp + (size_t)i*4) = float4{o[0],o[1],o[2],o[3]};
        }
    }
    #pragma unroll
    for (int q = 0; q < 16; q++){
        float s = v[q];
        s += __shfl_xor(s, 1);  s += __shfl_xor(s, 2);  s += __shfl_xor(s, 4);
        s += __shfl_xor(s, 8);  s += __shfl_xor(s, 16); s += __shfl_xor(s, 32);
        v[q] = s;
    }
    int lane = t & 63, wv = t >> 6;
    if (lane < 16) wsum[wv][lane] = v[lane];
    __syncthreads();
    if (t < 16)
        partials[(size_t)blockIdx.x*16 + t] = wsum[0][t] + wsum[1][t] + wsum[2][t] + wsum[3][t];
}

// fallback: one layer's a_edge in canonical order
__global__ void k_aedge1(const float* __restrict__ ea, const int* __restrict__ perm2, int E,
                         const float* __restrict__ Ve, int l, float* __restrict__ aout){
    __shared__ float vsm[64];
    if (threadIdx.x < 64) vsm[threadIdx.x] = Ve[l*64 + threadIdx.x];
    __syncthreads();
    int i = blockIdx.x*blockDim.x + threadIdx.x;
    if (i >= E) return;
    int e = perm2[i];
    const float4* p = (const float4*)(ea + (size_t)e*EDIM_);
    float v[16];
    #pragma unroll
    for (int q = 0; q < 4; q++){ float4 x = p[q]; v[q*4]=x.x; v[q*4+1]=x.y; v[q*4+2]=x.z; v[q*4+3]=x.w; }
    float o[4];
    #pragma unroll
    for (int h = 0; h < 4; h++){
        float s = 0.f;
        #pragma unroll
        for (int k = 0; k < EDIM_; k++) s += v[k]*vsm[k*4 + h];
        o[h] = s;
    }
    *(float4*)(aout + (size_t)i*4) = float4{o[0],o[1],o[2],o[3]};
}

__global__ void k_eamean(const float* __restrict__ ea, int E, float* __restrict__ partials){
    int t = threadIdx.x;
    size_t total = (size_t)E*4;
    float4 acc = {0,0,0,0};
    for (size_t i = (size_t)blockIdx.x*blockDim.x + t; i < total; i += (size_t)gridDim.x*blockDim.x){
        float4 v = ((const float4*)ea)[i];
        acc.x += v.x; acc.y += v.y; acc.z += v.z; acc.w += v.w;
    }
    __shared__ float4 sm[256];
    sm[t] = acc; __syncthreads();
    for (int off = 128; off >= 4; off >>= 1){
        if (t < off){
            sm[t].x += sm[t+off].x; sm[t].y += sm[t+off].y;
            sm[t].z += sm[t+off].z; sm[t].w += sm[t+off].w;
        }
        __syncthreads();
    }
    if (t < 4) ((float4*)partials)[(size_t)blockIdx.x*4 + t] = sm[t];
}

__global__ void k_colfin(const float* __restrict__ partials, int nb,
                         const float* __restrict__ Ve, float invE,
                         float* __restrict__ selfae){
    __shared__ float sm[256];
    int t = threadIdx.x;
    int col = t & 15, grp = t >> 4;
    float s = 0.f;
    for (int r = grp; r < nb; r += 16) s += partials[(size_t)r*16 + col];
    sm[grp*16 + col] = s;
    __syncthreads();
    if (t < 16){
        float tot = 0.f;
        #pragma unroll
        for (int g = 0; g < 16; g++) tot += sm[g*16 + t];
        sm[t] = tot;
    }
    __syncthreads();
    if (t < 12){
        int l = t/4, h = t%4; float s2 = 0.f;
        #pragma unroll
        for (int k = 0; k < EDIM_; k++) s2 += sm[k]*invE*Ve[l*64 + k*4 + h];
        selfae[t] = s2;
    }
}

// setup: Ve (192 values) + Wsd (256 values) in one launch
__global__ void k_setup(const float* __restrict__ We0, const float* __restrict__ ae0,
                        const float* __restrict__ We1, const float* __restrict__ ae1,
                        const float* __restrict__ We2, const float* __restrict__ ae2,
                        float* __restrict__ Ve,
                        const float* __restrict__ W3, const float* __restrict__ as3,
                        const float* __restrict__ ad3, float* __restrict__ Wsd){
    int t = threadIdx.x;
    if (t < 192){
        int l = t/64, r = t%64, k = r/4, h = r%4;
        const float* We = (l==0) ? We0 : (l==1) ? We1 : We2;
        const float* ae = (l==0) ? ae0 : (l==1) ? ae1 : ae2;
        float s = 0.f;
        for (int c = 0; c < HID_; c++) s += We[k*DH + h*HID_ + c] * ae[h*HID_ + c];
        Ve[t] = s;
    }
    {
        int k = t >> 3, r = t & 7, h = r & 3;
        const float* att = (r >= 4) ? ad3 : as3;
        float s = 0.f;
        for (int c = 0; c < HID_; c++) s += W3[k*DH + h*HID_ + c]*att[h*HID_ + c];
        Wsd[k*8 + r] = s;
    }
}

// ---------------- GEMM: [N,128]@[128,128], 64 rows/block, 8x4 per-thread tile.
template<int FBN>
__global__ __launch_bounds__(256) void k_gemm128(const float* __restrict__ X, const float* __restrict__ W,
        const float* __restrict__ attS, const float* __restrict__ attD,
        const float* __restrict__ stats, const float* __restrict__ g, const float* __restrict__ be,
        float invN,
        float* __restrict__ h, float* __restrict__ asrc, float* __restrict__ adst, int N){
    __shared__ float xs[64*128];      // 32 KB
    __shared__ float4 Ws[32*32];      // 16 KB
    __shared__ float scs[128], bos[128];
    int t = threadIdx.x;
    if (FBN){
        if (t < 128){
            float mu = stats[t]*invN;
            float var = stats[128+t]*invN - mu*mu;
            float sc = rsqrtf(var + 1e-5f)*g[t];
            scs[t] = sc; bos[t] = be[t] - mu*sc;
        }
        __syncthreads();
    }
    int nbase = blockIdx.x*64;
    const float4* xg = (const float4*)(X + (size_t)nbase*DH);
    for (int i = t; i < 64*32; i += 256){
        int row = i >> 5;
        float4 v = (nbase + row < N) ? xg[i] : float4{0,0,0,0};
        if (FBN){
            int f = (i & 31)*4;
            v.x = elu_(v.x*scs[f]   + bos[f]);
            v.y = elu_(v.y*scs[f+1] + bos[f+1]);
            v.z = elu_(v.z*scs[f+2] + bos[f+2]);
            v.w = elu_(v.w*scs[f+3] + bos[f+3]);
        }
        ((float4*)xs)[i] = v;
    }
    int rr = t >> 5;
    int cg = t & 31;
    float4 acc[8];
    #pragma unroll
    for (int i = 0; i < 8; i++) acc[i] = float4{0,0,0,0};
    const float4* Wg = (const float4*)W;
    for (int kc = 0; kc < 128; kc += 32){
        __syncthreads();
        for (int i = t; i < 32*32; i += 256) Ws[i] = Wg[(kc + (i>>5))*32 + (i&31)];
        __syncthreads();
        #pragma unroll
        for (int k4 = 0; k4 < 8; k4++){
            float4 xv[8];
            #pragma unroll
            for (int i = 0; i < 8; i++)
                xv[i] = *(const float4*)&xs[(rr + 8*i)*128 + kc + k4*4];
            #pragma unroll
            for (int j = 0; j < 4; j++){
                float4 w = Ws[(k4*4 + j)*32 + cg];
                #pragma unroll
                for (int i = 0; i < 8; i++){
                    float xj = (j==0) ? xv[i].x : (j==1) ? xv[i].y : (j==2) ? xv[i].z : xv[i].w;
                    acc[i].x += xj*w.x; acc[i].y += xj*w.y; acc[i].z += xj*w.z; acc[i].w += xj*w.w;
                }
            }
        }
    }
    int hd = cg >> 3;
    float4 as4 = *(const float4*)(attS + hd*HID_ + (cg&7)*4);
    float4 ad4 = *(const float4*)(attD + hd*HID_ + (cg&7)*4);
    #pragma unroll
    for (int i = 0; i < 8; i++){
        int n = nbase + rr + 8*i;
        float ps = acc[i].x*as4.x + acc[i].y*as4.y + acc[i].z*as4.z + acc[i].w*as4.w;
        float pd = acc[i].x*ad4.x + acc[i].y*ad4.y + acc[i].z*ad4.z + acc[i].w*ad4.w;
        ps += __shfl_xor(ps,1); ps += __shfl_xor(ps,2); ps += __shfl_xor(ps,4);
        pd += __shfl_xor(pd,1); pd += __shfl_xor(pd,2); pd += __shfl_xor(pd,4);
        if (n < N){
            *(float4*)(h + (size_t)n*DH + cg*4) = acc[i];
            if ((cg & 7) == 0){ asrc[n*4 + hd] = ps; adst[n*4 + hd] = pd; }
        }
    }
}

// GAT edge phase, layers 1/2: 4 nodes/wave, 16 lanes/node, serial edges, fused BN partials
template<int CONCAT>
__global__ __launch_bounds__(256) void k_aggL(const int* __restrict__ rowst, const int* __restrict__ srcs,
        const float* __restrict__ asrc, const float* __restrict__ adst, const float* __restrict__ aedge,
        const float* __restrict__ h, const float* __restrict__ selfae4,
        const float* __restrict__ bias, float* __restrict__ out, float* __restrict__ spart, int N){
    __shared__ float smC[16][128];
    int t = threadIdx.x;
    int lane = t & 63, wv = t >> 6;
    int grp = lane >> 4;
    int fl  = lane & 15;
    int hd  = fl >> 2;
    int f   = fl*8;
    int node = wv*4 + grp;
    int n = blockIdx.x*16 + node;
    bool active = n < N;
    int st = 0, en = 0;
    float dvh = 0.f;
    if (active){
        st = rowst[n]; en = rowst[n+1];
        dvh = adst[(size_t)n*4 + hd];
    }
    float4 acc0 = {0,0,0,0}, acc1 = {0,0,0,0};
    float dsum = 0.f;
    for (int i = st; i < en; i++){
        int s = srcs[i];
        float w = __expf(lrelu(asrc[(size_t)s*4 + hd] + dvh + aedge[(size_t)i*4 + hd]));
        dsum += w;
        const float4* hp = (const float4*)(h + (size_t)s*DH + f);
        float4 a = hp[0], b4 = hp[1];
        acc0.x += w*a.x;  acc0.y += w*a.y;  acc0.z += w*a.z;  acc0.w += w*a.w;
        acc1.x += w*b4.x; acc1.y += w*b4.y; acc1.z += w*b4.z; acc1.w += w*b4.w;
    }
    if (active){
        float es = __expf(lrelu(asrc[(size_t)n*4 + hd] + dvh + selfae4[hd]));
        float invd = 1.f/(dsum + es + 1e-16f);
        const float4* hnp = (const float4*)(h + (size_t)n*DH + f);
        float4 hnA = hnp[0], hnB = hnp[1];
        acc0.x = (acc0.x + es*hnA.x)*invd; acc0.y = (acc0.y + es*hnA.y)*invd;
        acc0.z = (acc0.z + es*hnA.z)*invd; acc0.w = (acc0.w + es*hnA.w)*invd;
        acc1.x = (acc1.x + es*hnB.x)*invd; acc1.y = (acc1.y + es*hnB.y)*invd;
        acc1.z = (acc1.z + es*hnB.z)*invd; acc1.w = (acc1.w + es*hnB.w)*invd;
    }
    if (CONCAT){
        float4 oA = {0,0,0,0}, oB = {0,0,0,0};
        if (active){
            const float* b4 = bias + f;
            oA = float4{acc0.x + b4[0], acc0.y + b4[1], acc0.z + b4[2], acc0.w + b4[3]};
            oB = float4{acc1.x + b4[4], acc1.y + b4[5], acc1.z + b4[6], acc1.w + b4[7]};
            *(float4*)(out + (size_t)n*DH + f)     = oA;
            *(float4*)(out + (size_t)n*DH + f + 4) = oB;
        }
        *(float4*)&smC[node][f]     = oA;
        *(float4*)&smC[node][f + 4] = oB;
    } else {
        #pragma unroll
        for (int msk = 4; msk <= 8; msk <<= 1){
            acc0.x += __shfl_xor(acc0.x, msk); acc0.y += __shfl_xor(acc0.y, msk);
            acc0.z += __shfl_xor(acc0.z, msk); acc0.w += __shfl_xor(acc0.w, msk);
            acc1.x += __shfl_xor(acc1.x, msk); acc1.y += __shfl_xor(acc1.y, msk);
            acc1.z += __shfl_xor(acc1.z, msk); acc1.w += __shfl_xor(acc1.w, msk);
        }
        if (fl < 4){
            int c = fl*8;
            float4 oA = {0,0,0,0}, oB = {0,0,0,0};
            if (active){
                const float* b4 = bias + c;
                oA = float4{0.25f*acc0.x + b4[0], 0.25f*acc0.y + b4[1],
                            0.25f*acc0.z + b4[2], 0.25f*acc0.w + b4[3]};
                oB = float4{0.25f*acc1.x + b4[4], 0.25f*acc1.y + b4[5],
                            0.25f*acc1.z + b4[6], 0.25f*acc1.w + b4[7]};
                *(float4*)(out + (size_t)n*HID_ + c)     = oA;
                *(float4*)(out + (size_t)n*HID_ + c + 4) = oB;
            }
            *(float4*)&smC[node][c]     = oA;
            *(float4*)&smC[node][c + 4] = oB;
        }
    }
    __syncthreads();
    const int D = CONCAT ? 128 : 32;
    if (t < D){
        float s = 0.f, s2 = 0.f;
        #pragma unroll 4
        for (int r = 0; r < 16; r++){
            float v = smC[r][t];
            s += v; s2 += v*v;
        }
        spart[(size_t)blockIdx.x*2*D + t]     = s;
        spart[(size_t)blockIdx.x*2*D + D + t] = s2;
    }
}

// Layer 3 edge phase: 8 nodes/wave, 8 lanes/node, writes per-head agg[N,128].
__global__ __launch_bounds__(256) void k_aggA(const int* __restrict__ rowst, const int* __restrict__ srcs,
        const float* __restrict__ asrc, const float* __restrict__ adst, const float* __restrict__ aedge,
        const float* __restrict__ A, const float* __restrict__ selfae4,
        float* __restrict__ agg, int N){
    int t = threadIdx.x;
    int lane = t & 63, wv = t >> 6;
    int grp = lane >> 3;
    int fl  = lane & 7;
    int f   = fl*4;
    int n = blockIdx.x*32 + wv*8 + grp;
    bool active = n < N;
    int st = 0, en = 0;
    float4 dv = {0,0,0,0};
    if (active){
        st = rowst[n]; en = rowst[n+1];
        dv = *(const float4*)(adst + (size_t)n*4);
    }
    float4 acc0 = {0,0,0,0}, acc1 = {0,0,0,0}, acc2 = {0,0,0,0}, acc3 = {0,0,0,0};
    float4 dsum = {0,0,0,0};
    for (int i = st; i < en; i++){
        int s = srcs[i];
        float4 av = *(const float4*)(asrc + (size_t)s*4);
        float4 ae4 = *(const float4*)(aedge + (size_t)i*4);
        float w0 = __expf(lrelu(av.x + dv.x + ae4.x));
        float w1 = __expf(lrelu(av.y + dv.y + ae4.y));
        float w2 = __expf(lrelu(av.z + dv.z + ae4.z));
        float w3 = __expf(lrelu(av.w + dv.w + ae4.w));
        dsum.x += w0; dsum.y += w1; dsum.z += w2; dsum.w += w3;
        float4 a = *(const float4*)(A + (size_t)s*HID_ + f);
        acc0.x += w0*a.x; acc0.y += w0*a.y; acc0.z += w0*a.z; acc0.w += w0*a.w;
        acc1.x += w1*a.x; acc1.y += w1*a.y; acc1.z += w1*a.z; acc1.w += w1*a.w;
        acc2.x += w2*a.x; acc2.y += w2*a.y; acc2.z += w2*a.z; acc2.w += w2*a.w;
        acc3.x += w3*a.x; acc3.y += w3*a.y; acc3.z += w3*a.z; acc3.w += w3*a.w;
    }
    if (active){
        float4 av = *(const float4*)(asrc + (size_t)n*4);
        float4 sa = *(const float4*)selfae4;
        float e0 = __expf(lrelu(av.x + dv.x + sa.x));
        float e1 = __expf(lrelu(av.y + dv.y + sa.y));
        float e2 = __expf(lrelu(av.z + dv.z + sa.z));
        float e3 = __expf(lrelu(av.w + dv.w + sa.w));
        float4 aself = *(const float4*)(A + (size_t)n*HID_ + f);
        float i0 = 1.f/(dsum.x + e0 + 1e-16f);
        float i1 = 1.f/(dsum.y + e1 + 1e-16f);
        float i2 = 1.f/(dsum.z + e2 + 1e-16f);
        float i3 = 1.f/(dsum.w + e3 + 1e-16f);
        acc0.x = (acc0.x + e0*aself.x)*i0; acc0.y = (acc0.y + e0*aself.y)*i0;
        acc0.z = (acc0.z + e0*aself.z)*i0; acc0.w = (acc0.w + e0*aself.w)*i0;
        acc1.x = (acc1.x + e1*aself.x)*i1; acc1.y = (acc1.y + e1*aself.y)*i1;
        acc1.z = (acc1.z + e1*aself.z)*i1; acc1.w = (acc1.w + e1*aself.w)*i1;
        acc2.x = (acc2.x + e2*aself.x)*i2; acc2.y = (acc2.y + e2*aself.y)*i2;
        acc2.z = (acc2.z + e2*aself.z)*i2; acc2.w = (acc2.w + e2*aself.w)*i2;
        acc3.x = (acc3.x + e3*aself.x)*i3; acc3.y = (acc3.y + e3*aself.y)*i3;
        acc3.z = (acc3.z + e3*aself.z)*i3; acc3.w = (acc3.w + e3*aself.w)*i3;
        float* ap = agg + (size_t)n*DH;
        *(float4*)(ap +  0 + f) = acc0;
        *(float4*)(ap + 32 + f) = acc1;
        *(float4*)(ap + 64 + f) = acc2;
        *(float4*)(ap + 96 + f) = acc3;
    }
}

// C3 = 0.25*agg@Wmix + b3, 32 rows/block, fused BN stats
__global__ __launch_bounds__(256) void k_w3mix(const float* __restrict__ agg,
        const float* __restrict__ W3, const float* __restrict__ b3,
        float* __restrict__ C, float* __restrict__ spart, int N){
    __shared__ float as_[32*132];
    __shared__ float wf[128*32];
    __shared__ float ob[32];
    int t = threadIdx.x;
    for (int i = t; i < 4096; i += 256){
        int kk = i >> 5, c = i & 31;
        int hh = kk >> 5, k = kk & 31;
        wf[i] = W3[k*DH + hh*HID_ + c];
    }
    if (t < 32) ob[t] = b3[t];
    int nbase = blockIdx.x*32;
    const float4* ag = (const float4*)(agg + (size_t)nbase*DH);
    for (int i = t; i < 32*32; i += 256){
        int row = i >> 5, col4 = i & 31;
        float4 v = (nbase + row < N) ? ag[i] : float4{0,0,0,0};
        *(float4*)&as_[row*132 + col4*4] = v;
    }
    __syncthreads();
    int rg = t >> 3;
    int cq = t & 7;
    int n = nbase + rg;
    float4 acc = {0,0,0,0};
    const float* xr = &as_[rg*132];
    const float4* wf4 = (const float4*)wf;
    #pragma unroll 8
    for (int k = 0; k < 128; k++){
        float xv = xr[k];
        float4 w = wf4[k*8 + cq];
        acc.x += xv*w.x; acc.y += xv*w.y; acc.z += xv*w.z; acc.w += xv*w.w;
    }
    float4 o = {0,0,0,0};
    if (n < N){
        o = float4{0.25f*acc.x + ob[cq*4], 0.25f*acc.y + ob[cq*4+1],
                   0.25f*acc.z + ob[cq*4+2], 0.25f*acc.w + ob[cq*4+3]};
        *(float4*)(C + (size_t)n*HID_ + cq*4) = o;
    }
    __syncthreads();
    *(float4*)&as_[rg*132 + cq*4] = o;
    __syncthreads();
    if (t < 32){
        float s = 0.f, s2 = 0.f;
        #pragma unroll 4
        for (int r = 0; r < 32; r++){
            float v = as_[r*132 + t];
            s += v; s2 += v*v;
        }
        spart[(size_t)blockIdx.x*64 + t]      = s;
        spart[(size_t)blockIdx.x*64 + 32 + t] = s2;
    }
}

// asrc/adst for layer 3 from A [N,32]
__global__ void k_attn3(const float* __restrict__ A, int N, const float* __restrict__ Wsd,
                        float* __restrict__ asrc, float* __restrict__ adst){
    __shared__ float ws[256];
    ws[threadIdx.x] = Wsd[threadIdx.x & 255];
    __syncthreads();
    int n = blockIdx.x*blockDim.x + threadIdx.x;
    if (n >= N) return;
    float s[8] = {0,0,0,0,0,0,0,0};
    const float4* ar = (const float4*)(A + (size_t)n*HID_);
    #pragma unroll
    for (int kq = 0; kq < 8; kq++){
        float4 a = ar[kq];
        const float* w0 = &ws[kq*32];
        #pragma unroll
        for (int r = 0; r < 8; r++)
            s[r] += a.x*w0[r] + a.y*w0[8+r] + a.z*w0[16+r] + a.w*w0[24+r];
    }
    *(float4*)(asrc + (size_t)n*4) = float4{s[0],s[1],s[2],s[3]};
    *(float4*)(adst + (size_t)n*4) = float4{s[4],s[5],s[6],s[7]};
}

// two-stage BN-partials reduction: stage 1 = 64 blocks, each reduces a fixed chunk
__global__ void k_statsred1(const float* __restrict__ spart, int nb, int D,
                            float* __restrict__ spart2){
    int t = threadIdx.x;
    if (t >= 2*D) return;
    int K = (nb + gridDim.x - 1)/gridDim.x;
    int b0 = blockIdx.x*K;
    int b1 = min(nb, b0 + K);
    float a0=0.f, a1=0.f, a2=0.f, a3=0.f;
    int b = b0;
    for (; b + 4 <= b1; b += 4){
        a0 += spart[(size_t)b*2*D + t];
        a1 += spart[(size_t)(b+1)*2*D + t];
        a2 += spart[(size_t)(b+2)*2*D + t];
        a3 += spart[(size_t)(b+3)*2*D + t];
    }
    float s = (a0 + a1) + (a2 + a3);
    for (; b < b1; b++) s += spart[(size_t)b*2*D + t];
    spart2[(size_t)blockIdx.x*2*D + t] = s;
}

// stage 2: reduce the 64 chunk rows
__global__ void k_statsred(const float* __restrict__ spart, int nb, int D,
                           float* __restrict__ stats){
    int t = threadIdx.x;
    if (t >= 2*D) return;
    float a0=0.f, a1=0.f, a2=0.f, a3=0.f;
    int b = 0;
    for (; b + 4 <= nb; b += 4){
        a0 += spart[(size_t)b*2*D + t];
        a1 += spart[(size_t)(b+1)*2*D + t];
        a2 += spart[(size_t)(b+2)*2*D + t];
        a3 += spart[(size_t)(b+3)*2*D + t];
    }
    float s = (a0 + a1) + (a2 + a3);
    for (; b < nb; b++) s += spart[(size_t)b*2*D + t];
    stats[t < D ? t : 128 + (t - D)] = s;
}

__global__ void k_bnapply(const float* __restrict__ C, int N, int D,
                          const float* __restrict__ stats, const float* __restrict__ g,
                          const float* __restrict__ b, float* __restrict__ A){
    int idx = blockIdx.x*blockDim.x + threadIdx.x;
    if (idx >= N*D) return;
    int f = idx % D;
    float invN = 1.f/(float)N;
    float mu = stats[f]*invN;
    float var = stats[128 + f]*invN - mu*mu;
    float sc = rsqrtf(var + 1e-5f)*g[f];
    float y = (C[idx] - mu)*sc + b[f];
    A[idx] = elu_(y);
}

// pooling + fc, one block per graph, BN3+elu fused on load
__global__ __launch_bounds__(256) void k_poolfc(const float* __restrict__ C, int N,
        const float* __restrict__ stats, const float* __restrict__ g3, const float* __restrict__ be3,
        float invN,
        const float* __restrict__ gw, const float* __restrict__ gb,
        const int* __restrict__ batch, float* __restrict__ exg,
        const float* __restrict__ fcW, const float* __restrict__ fcb,
        float* __restrict__ out){
    int gId = blockIdx.x;
    int t = threadIdx.x;
    int lo = 0, hi = N;
    while (lo < hi){ int mid = (lo+hi) >> 1; if (batch[mid] < gId) lo = mid+1; else hi = mid; }
    int st = lo;
    hi = N;
    while (lo < hi){ int mid = (lo+hi) >> 1; if (batch[mid] < gId+1) lo = mid+1; else hi = mid; }
    int en = lo;

    __shared__ float gws[32];
    __shared__ float scs[32], bos[32];
    __shared__ float red[256];
    if (t < 32){
        gws[t] = gw[t];
        float mu = stats[t]*invN;
        float var = stats[128+t]*invN - mu*mu;
        float sc = rsqrtf(var + 1e-5f)*g3[t];
        scs[t] = sc; bos[t] = be3[t] - mu*sc;
    }
    __syncthreads();

    float den = 0.f;
    for (int n = st + t; n < en; n += 256){
        const float4* xr = (const float4*)(C + (size_t)n*HID_);
        float s = 0.f;
        #pragma unroll
        for (int q = 0; q < 8; q++){
            float4 v = xr[q];
            int f = q*4;
            s += elu_(v.x*scs[f]   + bos[f])  *gws[f]
               + elu_(v.y*scs[f+1] + bos[f+1])*gws[f+1]
               + elu_(v.z*scs[f+2] + bos[f+2])*gws[f+2]
               + elu_(v.w*scs[f+3] + bos[f+3])*gws[f+3];
        }
        float ex = __expf(s + gb[0]);
        exg[n] = ex;
        den += ex;
    }
    red[t] = den; __syncthreads();
    for (int off = 128; off > 0; off >>= 1){
        if (t < off) red[t] += red[t+off];
        __syncthreads();
    }
    float invd = 1.f/(red[0] + 1e-16f);
    __syncthreads();

    int c = t & 31, rg = t >> 5;
    float acc = 0.f;
    for (int n = st + rg; n < en; n += 8)
        acc += exg[n]*elu_(C[(size_t)n*HID_ + c]*scs[c] + bos[c]);
    red[t] = acc; __syncthreads();
    if (t < 128) red[t] += red[t+128];
    __syncthreads();
    if (t < 64) red[t] += red[t+64];
    __syncthreads();
    if (t < 32) red[t] += red[t+32];
    __syncthreads();
    if (t < 2){
        float s = 0.f;
        for (int cc = 0; cc < 32; cc++) s += red[cc]*invd*fcW[cc*2 + t];
        out[gId*2 + t] = s + fcb[t];
    }
}

extern "C" void kernel_launch(void* const* d_in, const int* in_sizes, int n_in,
                              void* d_out, int out_size, void* d_ws, size_t ws_size,
                              hipStream_t stream){
    const float* x   = (const float*)d_in[0];
    const int*   src = (const int*)d_in[1];
    const int*   dst = (const int*)d_in[2];
    const float* ea  = (const float*)d_in[3];
    const int* batch = (const int*)d_in[4];
    const float *W1=(const float*)d_in[5],  *as1=(const float*)d_in[6],  *ad1=(const float*)d_in[7];
    const float *We1=(const float*)d_in[8], *ae1=(const float*)d_in[9],  *b1=(const float*)d_in[10];
    const float *W2=(const float*)d_in[11], *as2=(const float*)d_in[12], *ad2=(const float*)d_in[13];
    const float *We2=(const float*)d_in[14],*ae2=(const float*)d_in[15], *b2=(const float*)d_in[16];
    const float *W3=(const float*)d_in[17], *as3=(const float*)d_in[18], *ad3=(const float*)d_in[19];
    const float *We3=(const float*)d_in[20],*ae3=(const float*)d_in[21], *b3=(const float*)d_in[22];
    const float *g1=(const float*)d_in[23], *be1=(const float*)d_in[24];
    const float *g2=(const float*)d_in[25], *be2=(const float*)d_in[26];
    const float *g3=(const float*)d_in[27], *be3=(const float*)d_in[28];
    const float *gw=(const float*)d_in[29], *gb=(const float*)d_in[30];
    const float *fcW=(const float*)d_in[31],*fcb=(const float*)d_in[32];
    int N = in_sizes[0]/DH;
    int E = in_sizes[1];
    float invN = 1.f/(float)N;

    const int tb = 256;
    int gE = (E + tb - 1)/tb;
    int nP = (gE > 1024) ? gE : 1024;
    int gL = (N + 15)/16;
    int gMix = (N + 31)/32;
    size_t spartN = (size_t)gL*256;
    const int RED1 = 64;

    float* ws = (float*)d_ws;
    size_t off = 0;
    float* A = ws + off;    off += (size_t)N*DH;
    float* B = ws + off;    off += (size_t)N*DH;
    float* C = ws + off;    off += (size_t)N*DH;
    float* asrc = ws + off; off += (size_t)N*4;
    float* adst = ws + off; off += (size_t)N*4;
    int* ints   = (int*)(ws + off);
    int* srcs   = ints;
    int* dsts   = ints + (size_t)E;
    int* perm   = ints + 2*(size_t)E;
    int* srcs2  = ints + 3*(size_t)E;
    int* perm2  = ints + 4*(size_t)E;
    int* rowst  = ints + 5*(size_t)E;
    int* counts = rowst + (N + 1);
    int* cursor = counts + N;
    int* bsums  = cursor + N;
    off += 5*(size_t)E + (N + 1) + 2*(size_t)N + 256;
    off = (off + 3) & ~(size_t)3;
    float* Ve     = ws + off;      // 192
    float* selfae = Ve + 192;      // 16
    float* stats  = selfae + 16;   // 3*256
    float* Wsd    = stats + 768;   // 256
    float* exg    = Wsd + 256;     // N
    float* partials = exg + N;     // nP*16
    float* spart  = partials + (size_t)nP*16;
    float* spart2 = spart + spartN;   // RED1*256
    off += 192 + 16 + 768 + 256 + (size_t)N + (size_t)nP*16 + spartN + (size_t)RED1*256;
    bool full = (off + (size_t)E*12)*sizeof(float) <= ws_size;
    float* ae0 = ws + off;
    float* ae1b = full ? ae0 + (size_t)E*4 : ae0;
    float* ae2b = full ? ae0 + (size_t)E*8 : ae0;

    hipMemsetAsync(counts, 0, (size_t)(2*N + 256)*sizeof(int), stream);

    int nb = (N + 511)/512;
    k_hist<<<gE, tb, 0, stream>>>(dst, E, counts);
    k_scan1<<<nb, 512, 0, stream>>>(counts, N, rowst, bsums);
    k_scan2<<<1, 1, 0, stream>>>(bsums, nb);
    k_scan3<<<(N + tb - 1)/tb, tb, 0, stream>>>(rowst, bsums, N, E);
    k_setup<<<1, 256, 0, stream>>>(We1, ae1, We2, ae2, We3, ae3, Ve, W3, as3, ad3, Wsd);
    k_scatter<<<gE, tb, 0, stream>>>(src, dst, E, rowst, cursor, srcs, dsts, perm);
    k_rank<<<gE, tb, 0, stream>>>(srcs, dsts, perm, rowst, E, srcs2, perm2);
    if (full){
        k_aedge3<<<gE, tb, 0, stream>>>(ea, perm2, E, Ve, ae0, ae1b, ae2b, partials);
        k_colfin<<<1, 256, 0, stream>>>(partials, gE, Ve, 1.f/(float)E, selfae);
    } else {
        k_eamean<<<1024, 256, 0, stream>>>(ea, E, partials);
        k_colfin<<<1, 256, 0, stream>>>(partials, 1024, Ve, 1.f/(float)E, selfae);
    }

    int gG = (N + 63)/64;
    // layer 1 (concat)
    k_gemm128<0><<<gG, 256, 0, stream>>>(x, W1, as1, ad1, stats, g1, be1, invN, B, asrc, adst, N);
    if (!full) k_aedge1<<<gE, tb, 0, stream>>>(ea, perm2, E, Ve, 0, ae0);
    k_aggL<1><<<gL, 256, 0, stream>>>(rowst, srcs2, asrc, adst, ae0, B, selfae + 0, b1, C, spart, N);
    k_statsred1<<<RED1, 256, 0, stream>>>(spart, gL, DH, spart2);
    k_statsred<<<1, 256, 0, stream>>>(spart2, RED1, DH, stats);
    // layer 2 (mean); BN1+elu fused into gemm input
    k_gemm128<1><<<gG, 256, 0, stream>>>(C, W2, as2, ad2, stats, g1, be1, invN, B, asrc, adst, N);
    if (!full) k_aedge1<<<gE, tb, 0, stream>>>(ea, perm2, E, Ve, 1, ae1b);
    k_aggL<0><<<gL, 256, 0, stream>>>(rowst, srcs2, asrc, adst, ae1b, B, selfae + 4, b2, C, spart, N);
    k_statsred1<<<RED1, 256, 0, stream>>>(spart, gL, HID_, spart2);
    k_statsred<<<1, 256, 0, stream>>>(spart2, RED1, HID_, stats + 256);
    k_bnapply<<<((size_t)N*HID_ + tb - 1)/tb, tb, 0, stream>>>(C, N, HID_, stats + 256, g2, be2, A);
    // layer 3 (A-space aggregation; W3 as batched GEMM with fused stats)
    k_attn3<<<(N + tb - 1)/tb, tb, 0, stream>>>(A, N, Wsd, asrc, adst);
    if (!full) k_aedge1<<<gE, tb, 0, stream>>>(ea, perm2, E, Ve, 2, ae2b);
    k_aggA<<<(N + 31)/32, 256, 0, stream>>>(rowst, srcs2, asrc, adst, ae2b, A, selfae + 8, B, N);
    k_w3mix<<<gMix, 256, 0, stream>>>(B, W3, b3, C, spart, N);
    k_statsred1<<<RED1, 256, 0, stream>>>(spart, gMix, HID_, spart2);
    k_statsred<<<1, 256, 0, stream>>>(spart2, RED1, HID_, stats + 512);
    // pooling + fc (BN3 fused)
    k_poolfc<<<NG_, 256, 0, stream>>>(C, N, stats + 512, g3, be3, invN, gw, gb, batch, exg, fcW, fcb, (float*)d_out);
}

// Round 11
// 536.879 us; speedup vs baseline: 1.9346x; 1.0243x over previous
//
#include <hip/hip_runtime.h>
#include <math.h>

#define DH 128      // HEADS*HID
#define HID_ 32
#define HEADS_ 4
#define EDIM_ 16
#define NG_ 64

__device__ __forceinline__ float lrelu(float v){ return v > 0.f ? v : 0.2f*v; }
__device__ __forceinline__ float elu_(float v){ return v > 0.f ? v : (__expf(v)-1.f); }

// ---------------- CSR build ----------------
__global__ void k_hist(const int* __restrict__ dst, int E, int* __restrict__ counts){
    int e = blockIdx.x*blockDim.x + threadIdx.x;
    if (e < E) atomicAdd(&counts[dst[e]], 1);
}

__global__ void k_scan1(const int* __restrict__ counts, int N, int* __restrict__ rowst, int* __restrict__ bsums){
    __shared__ int s[512];
    int t = threadIdx.x; int i = blockIdx.x*512 + t;
    int v = (i < N) ? counts[i] : 0;
    s[t] = v; __syncthreads();
    for (int off = 1; off < 512; off <<= 1){
        int x = (t >= off) ? s[t-off] : 0;
        __syncthreads();
        s[t] += x;
        __syncthreads();
    }
    if (i < N) rowst[i] = s[t] - v;
    if (t == 511) bsums[blockIdx.x] = s[511];
}

__global__ void k_scan2(int* bsums, int nb){
    if (threadIdx.x == 0 && blockIdx.x == 0){
        int run = 0;
        for (int b = 0; b < nb; b++){ int v = bsums[b]; bsums[b] = run; run += v; }
    }
}

__global__ void k_scan3(int* rowst, const int* __restrict__ bsums, int N, int E){
    int i = blockIdx.x*blockDim.x + threadIdx.x;
    if (i < N) rowst[i] += bsums[i/512];
    if (i == 0) rowst[N] = E;
}

__global__ void k_scatter(const int* __restrict__ src, const int* __restrict__ dst, int E,
                          const int* __restrict__ rowst, int* __restrict__ cursor,
                          int* __restrict__ srcs, int* __restrict__ dsts, int* __restrict__ perm){
    int e = blockIdx.x*blockDim.x + threadIdx.x;
    if (e < E){
        int d = dst[e];
        int p = rowst[d] + atomicAdd(&cursor[d], 1);
        srcs[p] = src[e]; dsts[p] = d; perm[p] = e;
    }
}

// canonicalize order within each segment (sort by original edge id)
__global__ void k_rank(const int* __restrict__ srcs, const int* __restrict__ dsts,
                       const int* __restrict__ perm, const int* __restrict__ rowst, int E,
                       int* __restrict__ srcs2, int* __restrict__ perm2){
    int p = blockIdx.x*blockDim.x + threadIdx.x;
    if (p >= E) return;
    int d = dsts[p];
    int st = rowst[d], en = rowst[d+1];
    int myp = perm[p];
    int rank = 0;
    for (int q = st; q < en; q++)
        rank += (perm[q] < myp) ? 1 : 0;
    srcs2[st + rank] = srcs[p];
    perm2[st + rank] = myp;
}

// a_edge for 3 layers in canonical order + fused ea column partial sums
__global__ __launch_bounds__(256) void k_aedge3(const float* __restrict__ ea, const int* __restrict__ perm2,
                        int E, const float* __restrict__ Ve,
                        float* __restrict__ ae0, float* __restrict__ ae1, float* __restrict__ ae2,
                        float* __restrict__ partials){
    __shared__ float vsm[192];
    __shared__ float wsum[4][16];
    int t = threadIdx.x;
    if (t < 192) vsm[t] = Ve[t];
    __syncthreads();
    int i = blockIdx.x*blockDim.x + t;
    float v[16];
    #pragma unroll
    for (int q = 0; q < 16; q++) v[q] = 0.f;
    if (i < E){
        int e = perm2[i];
        const float4* p = (const float4*)(ea + (size_t)e*EDIM_);
        #pragma unroll
        for (int q = 0; q < 4; q++){ float4 x = p[q]; v[q*4]=x.x; v[q*4+1]=x.y; v[q*4+2]=x.z; v[q*4+3]=x.w; }
        #pragma unroll
        for (int l = 0; l < 3; l++){
            float o[4];
            #pragma unroll
            for (int h = 0; h < 4; h++){
                float s = 0.f;
                #pragma unroll
                for (int k = 0; k < EDIM_; k++) s += v[k]*vsm[l*64 + k*4 + h];
                o[h] = s;
            }
            float* dp = (l==0) ? ae0 : (l==1) ? ae1 : ae2;
            *(float4*)(dp + (size_t)i*4) = float4{o[0],o[1],o[2],o[3]};
        }
    }
    #pragma unroll
    for (int q = 0; q < 16; q++){
        float s = v[q];
        s += __shfl_xor(s, 1);  s += __shfl_xor(s, 2);  s += __shfl_xor(s, 4);
        s += __shfl_xor(s, 8);  s += __shfl_xor(s, 16); s += __shfl_xor(s, 32);
        v[q] = s;
    }
    int lane = t & 63, wv = t >> 6;
    if (lane < 16) wsum[wv][lane] = v[lane];
    __syncthreads();
    if (t < 16)
        partials[(size_t)blockIdx.x*16 + t] = wsum[0][t] + wsum[1][t] + wsum[2][t] + wsum[3][t];
}

// fallback: one layer's a_edge in canonical order
__global__ void k_aedge1(const float* __restrict__ ea, const int* __restrict__ perm2, int E,
                         const float* __restrict__ Ve, int l, float* __restrict__ aout){
    __shared__ float vsm[64];
    if (threadIdx.x < 64) vsm[threadIdx.x] = Ve[l*64 + threadIdx.x];
    __syncthreads();
    int i = blockIdx.x*blockDim.x + threadIdx.x;
    if (i >= E) return;
    int e = perm2[i];
    const float4* p = (const float4*)(ea + (size_t)e*EDIM_);
    float v[16];
    #pragma unroll
    for (int q = 0; q < 4; q++){ float4 x = p[q]; v[q*4]=x.x; v[q*4+1]=x.y; v[q*4+2]=x.z; v[q*4+3]=x.w; }
    float o[4];
    #pragma unroll
    for (int h = 0; h < 4; h++){
        float s = 0.f;
        #pragma unroll
        for (int k = 0; k < EDIM_; k++) s += v[k]*vsm[k*4 + h];
        o[h] = s;
    }
    *(float4*)(aout + (size_t)i*4) = float4{o[0],o[1],o[2],o[3]};
}

__global__ void k_eamean(const float* __restrict__ ea, int E, float* __restrict__ partials){
    int t = threadIdx.x;
    size_t total = (size_t)E*4;
    float4 acc = {0,0,0,0};
    for (size_t i = (size_t)blockIdx.x*blockDim.x + t; i < total; i += (size_t)gridDim.x*blockDim.x){
        float4 v = ((const float4*)ea)[i];
        acc.x += v.x; acc.y += v.y; acc.z += v.z; acc.w += v.w;
    }
    __shared__ float4 sm[256];
    sm[t] = acc; __syncthreads();
    for (int off = 128; off >= 4; off >>= 1){
        if (t < off){
            sm[t].x += sm[t+off].x; sm[t].y += sm[t+off].y;
            sm[t].z += sm[t+off].z; sm[t].w += sm[t+off].w;
        }
        __syncthreads();
    }
    if (t < 4) ((float4*)partials)[(size_t)blockIdx.x*4 + t] = sm[t];
}

__global__ void k_colfin(const float* __restrict__ partials, int nb,
                         const float* __restrict__ Ve, float invE,
                         float* __restrict__ selfae){
    __shared__ float sm[256];
    int t = threadIdx.x;
    int col = t & 15, grp = t >> 4;
    float s = 0.f;
    for (int r = grp; r < nb; r += 16) s += partials[(size_t)r*16 + col];
    sm[grp*16 + col] = s;
    __syncthreads();
    if (t < 16){
        float tot = 0.f;
        #pragma unroll
        for (int g = 0; g < 16; g++) tot += sm[g*16 + t];
        sm[t] = tot;
    }
    __syncthreads();
    if (t < 12){
        int l = t/4, h = t%4; float s2 = 0.f;
        #pragma unroll
        for (int k = 0; k < EDIM_; k++) s2 += sm[k]*invE*Ve[l*64 + k*4 + h];
        selfae[t] = s2;
    }
}

// setup: Ve (192 values) + Wsd (256 values) in one launch
__global__ void k_setup(const float* __restrict__ We0, const float* __restrict__ ae0,
                        const float* __restrict__ We1, const float* __restrict__ ae1,
                        const float* __restrict__ We2, const float* __restrict__ ae2,
                        float* __restrict__ Ve,
                        const float* __restrict__ W3, const float* __restrict__ as3,
                        const float* __restrict__ ad3, float* __restrict__ Wsd){
    int t = threadIdx.x;
    if (t < 192){
        int l = t/64, r = t%64, k = r/4, h = r%4;
        const float* We = (l==0) ? We0 : (l==1) ? We1 : We2;
        const float* ae = (l==0) ? ae0 : (l==1) ? ae1 : ae2;
        float s = 0.f;
        for (int c = 0; c < HID_; c++) s += We[k*DH + h*HID_ + c] * ae[h*HID_ + c];
        Ve[t] = s;
    }
    {
        int k = t >> 3, r = t & 7, h = r & 3;
        const float* att = (r >= 4) ? ad3 : as3;
        float s = 0.f;
        for (int c = 0; c < HID_; c++) s += W3[k*DH + h*HID_ + c]*att[h*HID_ + c];
        Wsd[k*8 + r] = s;
    }
}

// ---------------- GEMM: [N,128]@[128,128], 64 rows/block, 8x4 per-thread tile.
template<int FBN>
__global__ __launch_bounds__(256) void k_gemm128(const float* __restrict__ X, const float* __restrict__ W,
        const float* __restrict__ attS, const float* __restrict__ attD,
        const float* __restrict__ stats, const float* __restrict__ g, const float* __restrict__ be,
        float invN,
        float* __restrict__ h, float* __restrict__ asrc, float* __restrict__ adst, int N){
    __shared__ float xs[64*128];      // 32 KB
    __shared__ float4 Ws[32*32];      // 16 KB
    __shared__ float scs[128], bos[128];
    int t = threadIdx.x;
    if (FBN){
        if (t < 128){
            float mu = stats[t]*invN;
            float var = stats[128+t]*invN - mu*mu;
            float sc = rsqrtf(var + 1e-5f)*g[t];
            scs[t] = sc; bos[t] = be[t] - mu*sc;
        }
        __syncthreads();
    }
    int nbase = blockIdx.x*64;
    const float4* xg = (const float4*)(X + (size_t)nbase*DH);
    for (int i = t; i < 64*32; i += 256){
        int row = i >> 5;
        float4 v = (nbase + row < N) ? xg[i] : float4{0,0,0,0};
        if (FBN){
            int f = (i & 31)*4;
            v.x = elu_(v.x*scs[f]   + bos[f]);
            v.y = elu_(v.y*scs[f+1] + bos[f+1]);
            v.z = elu_(v.z*scs[f+2] + bos[f+2]);
            v.w = elu_(v.w*scs[f+3] + bos[f+3]);
        }
        ((float4*)xs)[i] = v;
    }
    int rr = t >> 5;
    int cg = t & 31;
    float4 acc[8];
    #pragma unroll
    for (int i = 0; i < 8; i++) acc[i] = float4{0,0,0,0};
    const float4* Wg = (const float4*)W;
    for (int kc = 0; kc < 128; kc += 32){
        __syncthreads();
        for (int i = t; i < 32*32; i += 256) Ws[i] = Wg[(kc + (i>>5))*32 + (i&31)];
        __syncthreads();
        #pragma unroll
        for (int k4 = 0; k4 < 8; k4++){
            float4 xv[8];
            #pragma unroll
            for (int i = 0; i < 8; i++)
                xv[i] = *(const float4*)&xs[(rr + 8*i)*128 + kc + k4*4];
            #pragma unroll
            for (int j = 0; j < 4; j++){
                float4 w = Ws[(k4*4 + j)*32 + cg];
                #pragma unroll
                for (int i = 0; i < 8; i++){
                    float xj = (j==0) ? xv[i].x : (j==1) ? xv[i].y : (j==2) ? xv[i].z : xv[i].w;
                    acc[i].x += xj*w.x; acc[i].y += xj*w.y; acc[i].z += xj*w.z; acc[i].w += xj*w.w;
                }
            }
        }
    }
    int hd = cg >> 3;
    float4 as4 = *(const float4*)(attS + hd*HID_ + (cg&7)*4);
    float4 ad4 = *(const float4*)(attD + hd*HID_ + (cg&7)*4);
    #pragma unroll
    for (int i = 0; i < 8; i++){
        int n = nbase + rr + 8*i;
        float ps = acc[i].x*as4.x + acc[i].y*as4.y + acc[i].z*as4.z + acc[i].w*as4.w;
        float pd = acc[i].x*ad4.x + acc[i].y*ad4.y + acc[i].z*ad4.z + acc[i].w*ad4.w;
        ps += __shfl_xor(ps,1); ps += __shfl_xor(ps,2); ps += __shfl_xor(ps,4);
        pd += __shfl_xor(pd,1); pd += __shfl_xor(pd,2); pd += __shfl_xor(pd,4);
        if (n < N){
            *(float4*)(h + (size_t)n*DH + cg*4) = acc[i];
            if ((cg & 7) == 0){ asrc[n*4 + hd] = ps; adst[n*4 + hd] = pd; }
        }
    }
}

// GAT edge phase, layers 1/2: 4 nodes/wave, 16 lanes/node, 2-edge-unrolled serial
// loop (doubled MLP), fused BN partials.
template<int CONCAT>
__global__ __launch_bounds__(256) void k_aggL(const int* __restrict__ rowst, const int* __restrict__ srcs,
        const float* __restrict__ asrc, const float* __restrict__ adst, const float* __restrict__ aedge,
        const float* __restrict__ h, const float* __restrict__ selfae4,
        const float* __restrict__ bias, float* __restrict__ out, float* __restrict__ spart, int N){
    __shared__ float smC[16][128];
    int t = threadIdx.x;
    int lane = t & 63, wv = t >> 6;
    int grp = lane >> 4;
    int fl  = lane & 15;
    int hd  = fl >> 2;
    int f   = fl*8;
    int node = wv*4 + grp;
    int n = blockIdx.x*16 + node;
    bool active = n < N;
    int st = 0, en = 0;
    float dvh = 0.f;
    if (active){
        st = rowst[n]; en = rowst[n+1];
        dvh = adst[(size_t)n*4 + hd];
    }
    float4 acc0 = {0,0,0,0}, acc1 = {0,0,0,0};
    float dsum = 0.f;
    int i = st;
    for (; i + 2 <= en; i += 2){
        int s0 = srcs[i];
        int s1 = srcs[i+1];
        float a0s = asrc[(size_t)s0*4 + hd];
        float a1s = asrc[(size_t)s1*4 + hd];
        float e0 = aedge[(size_t)i*4 + hd];
        float e1 = aedge[(size_t)(i+1)*4 + hd];
        const float4* hp0 = (const float4*)(h + (size_t)s0*DH + f);
        const float4* hp1 = (const float4*)(h + (size_t)s1*DH + f);
        float4 a0 = hp0[0], b0 = hp0[1];
        float4 a1 = hp1[0], b1 = hp1[1];
        float w0 = __expf(lrelu(a0s + dvh + e0));
        float w1 = __expf(lrelu(a1s + dvh + e1));
        dsum += w0;
        dsum += w1;
        acc0.x += w0*a0.x;  acc0.y += w0*a0.y;  acc0.z += w0*a0.z;  acc0.w += w0*a0.w;
        acc1.x += w0*b0.x;  acc1.y += w0*b0.y;  acc1.z += w0*b0.z;  acc1.w += w0*b0.w;
        acc0.x += w1*a1.x;  acc0.y += w1*a1.y;  acc0.z += w1*a1.z;  acc0.w += w1*a1.w;
        acc1.x += w1*b1.x;  acc1.y += w1*b1.y;  acc1.z += w1*b1.z;  acc1.w += w1*b1.w;
    }
    if (i < en){
        int s = srcs[i];
        float w = __expf(lrelu(asrc[(size_t)s*4 + hd] + dvh + aedge[(size_t)i*4 + hd]));
        dsum += w;
        const float4* hp = (const float4*)(h + (size_t)s*DH + f);
        float4 a = hp[0], b4 = hp[1];
        acc0.x += w*a.x;  acc0.y += w*a.y;  acc0.z += w*a.z;  acc0.w += w*a.w;
        acc1.x += w*b4.x; acc1.y += w*b4.y; acc1.z += w*b4.z; acc1.w += w*b4.w;
    }
    if (active){
        float es = __expf(lrelu(asrc[(size_t)n*4 + hd] + dvh + selfae4[hd]));
        float invd = 1.f/(dsum + es + 1e-16f);
        const float4* hnp = (const float4*)(h + (size_t)n*DH + f);
        float4 hnA = hnp[0], hnB = hnp[1];
        acc0.x = (acc0.x + es*hnA.x)*invd; acc0.y = (acc0.y + es*hnA.y)*invd;
        acc0.z = (acc0.z + es*hnA.z)*invd; acc0.w = (acc0.w + es*hnA.w)*invd;
        acc1.x = (acc1.x + es*hnB.x)*invd; acc1.y = (acc1.y + es*hnB.y)*invd;
        acc1.z = (acc1.z + es*hnB.z)*invd; acc1.w = (acc1.w + es*hnB.w)*invd;
    }
    if (CONCAT){
        float4 oA = {0,0,0,0}, oB = {0,0,0,0};
        if (active){
            const float* b4 = bias + f;
            oA = float4{acc0.x + b4[0], acc0.y + b4[1], acc0.z + b4[2], acc0.w + b4[3]};
            oB = float4{acc1.x + b4[4], acc1.y + b4[5], acc1.z + b4[6], acc1.w + b4[7]};
            *(float4*)(out + (size_t)n*DH + f)     = oA;
            *(float4*)(out + (size_t)n*DH + f + 4) = oB;
        }
        *(float4*)&smC[node][f]     = oA;
        *(float4*)&smC[node][f + 4] = oB;
    } else {
        #pragma unroll
        for (int msk = 4; msk <= 8; msk <<= 1){
            acc0.x += __shfl_xor(acc0.x, msk); acc0.y += __shfl_xor(acc0.y, msk);
            acc0.z += __shfl_xor(acc0.z, msk); acc0.w += __shfl_xor(acc0.w, msk);
            acc1.x += __shfl_xor(acc1.x, msk); acc1.y += __shfl_xor(acc1.y, msk);
            acc1.z += __shfl_xor(acc1.z, msk); acc1.w += __shfl_xor(acc1.w, msk);
        }
        if (fl < 4){
            int c = fl*8;
            float4 oA = {0,0,0,0}, oB = {0,0,0,0};
            if (active){
                const float* b4 = bias + c;
                oA = float4{0.25f*acc0.x + b4[0], 0.25f*acc0.y + b4[1],
                            0.25f*acc0.z + b4[2], 0.25f*acc0.w + b4[3]};
                oB = float4{0.25f*acc1.x + b4[4], 0.25f*acc1.y + b4[5],
                            0.25f*acc1.z + b4[6], 0.25f*acc1.w + b4[7]};
                *(float4*)(out + (size_t)n*HID_ + c)     = oA;
                *(float4*)(out + (size_t)n*HID_ + c + 4) = oB;
            }
            *(float4*)&smC[node][c]     = oA;
            *(float4*)&smC[node][c + 4] = oB;
        }
    }
    __syncthreads();
    const int D = CONCAT ? 128 : 32;
    if (t < D){
        float s = 0.f, s2 = 0.f;
        #pragma unroll 4
        for (int r = 0; r < 16; r++){
            float v = smC[r][t];
            s += v; s2 += v*v;
        }
        spart[(size_t)blockIdx.x*2*D + t]     = s;
        spart[(size_t)blockIdx.x*2*D + D + t] = s2;
    }
}

// Layer 3 edge phase: 8 nodes/wave, 8 lanes/node, 2-edge unrolled, writes agg[N,128].
__global__ __launch_bounds__(256) void k_aggA(const int* __restrict__ rowst, const int* __restrict__ srcs,
        const float* __restrict__ asrc, const float* __restrict__ adst, const float* __restrict__ aedge,
        const float* __restrict__ A, const float* __restrict__ selfae4,
        float* __restrict__ agg, int N){
    int t = threadIdx.x;
    int lane = t & 63, wv = t >> 6;
    int grp = lane >> 3;
    int fl  = lane & 7;
    int f   = fl*4;
    int n = blockIdx.x*32 + wv*8 + grp;
    bool active = n < N;
    int st = 0, en = 0;
    float4 dv = {0,0,0,0};
    if (active){
        st = rowst[n]; en = rowst[n+1];
        dv = *(const float4*)(adst + (size_t)n*4);
    }
    float4 acc0 = {0,0,0,0}, acc1 = {0,0,0,0}, acc2 = {0,0,0,0}, acc3 = {0,0,0,0};
    float4 dsum = {0,0,0,0};
    int i = st;
    for (; i + 2 <= en; i += 2){
        int s0 = srcs[i];
        int s1 = srcs[i+1];
        float4 av0 = *(const float4*)(asrc + (size_t)s0*4);
        float4 av1 = *(const float4*)(asrc + (size_t)s1*4);
        float4 ae0 = *(const float4*)(aedge + (size_t)i*4);
        float4 ae1 = *(const float4*)(aedge + (size_t)(i+1)*4);
        float4 a0 = *(const float4*)(A + (size_t)s0*HID_ + f);
        float4 a1 = *(const float4*)(A + (size_t)s1*HID_ + f);
        float w00 = __expf(lrelu(av0.x + dv.x + ae0.x));
        float w01 = __expf(lrelu(av0.y + dv.y + ae0.y));
        float w02 = __expf(lrelu(av0.z + dv.z + ae0.z));
        float w03 = __expf(lrelu(av0.w + dv.w + ae0.w));
        float w10 = __expf(lrelu(av1.x + dv.x + ae1.x));
        float w11 = __expf(lrelu(av1.y + dv.y + ae1.y));
        float w12 = __expf(lrelu(av1.z + dv.z + ae1.z));
        float w13 = __expf(lrelu(av1.w + dv.w + ae1.w));
        dsum.x += w00; dsum.y += w01; dsum.z += w02; dsum.w += w03;
        dsum.x += w10; dsum.y += w11; dsum.z += w12; dsum.w += w13;
        acc0.x += w00*a0.x; acc0.y += w00*a0.y; acc0.z += w00*a0.z; acc0.w += w00*a0.w;
        acc1.x += w01*a0.x; acc1.y += w01*a0.y; acc1.z += w01*a0.z; acc1.w += w01*a0.w;
        acc2.x += w02*a0.x; acc2.y += w02*a0.y; acc2.z += w02*a0.z; acc2.w += w02*a0.w;
        acc3.x += w03*a0.x; acc3.y += w03*a0.y; acc3.z += w03*a0.z; acc3.w += w03*a0.w;
        acc0.x += w10*a1.x; acc0.y += w10*a1.y; acc0.z += w10*a1.z; acc0.w += w10*a1.w;
        acc1.x += w11*a1.x; acc1.y += w11*a1.y; acc1.z += w11*a1.z; acc1.w += w11*a1.w;
        acc2.x += w12*a1.x; acc2.y += w12*a1.y; acc2.z += w12*a1.z; acc2.w += w12*a1.w;
        acc3.x += w13*a1.x; acc3.y += w13*a1.y; acc3.z += w13*a1.z; acc3.w += w13*a1.w;
    }
    if (i < en){
        int s = srcs[i];
        float4 av = *(const float4*)(asrc + (size_t)s*4);
        float4 ae4 = *(const float4*)(aedge + (size_t)i*4);
        float w0 = __expf(lrelu(av.x + dv.x + ae4.x));
        float w1 = __expf(lrelu(av.y + dv.y + ae4.y));
        float w2 = __expf(lrelu(av.z + dv.z + ae4.z));
        float w3 = __expf(lrelu(av.w + dv.w + ae4.w));
        dsum.x += w0; dsum.y += w1; dsum.z += w2; dsum.w += w3;
        float4 a = *(const float4*)(A + (size_t)s*HID_ + f);
        acc0.x += w0*a.x; acc0.y += w0*a.y; acc0.z += w0*a.z; acc0.w += w0*a.w;
        acc1.x += w1*a.x; acc1.y += w1*a.y; acc1.z += w1*a.z; acc1.w += w1*a.w;
        acc2.x += w2*a.x; acc2.y += w2*a.y; acc2.z += w2*a.z; acc2.w += w2*a.w;
        acc3.x += w3*a.x; acc3.y += w3*a.y; acc3.z += w3*a.z; acc3.w += w3*a.w;
    }
    if (active){
        float4 av = *(const float4*)(asrc + (size_t)n*4);
        float4 sa = *(const float4*)selfae4;
        float e0 = __expf(lrelu(av.x + dv.x + sa.x));
        float e1 = __expf(lrelu(av.y + dv.y + sa.y));
        float e2 = __expf(lrelu(av.z + dv.z + sa.z));
        float e3 = __expf(lrelu(av.w + dv.w + sa.w));
        float4 aself = *(const float4*)(A + (size_t)n*HID_ + f);
        float i0 = 1.f/(dsum.x + e0 + 1e-16f);
        float i1 = 1.f/(dsum.y + e1 + 1e-16f);
        float i2 = 1.f/(dsum.z + e2 + 1e-16f);
        float i3 = 1.f/(dsum.w + e3 + 1e-16f);
        acc0.x = (acc0.x + e0*aself.x)*i0; acc0.y = (acc0.y + e0*aself.y)*i0;
        acc0.z = (acc0.z + e0*aself.z)*i0; acc0.w = (acc0.w + e0*aself.w)*i0;
        acc1.x = (acc1.x + e1*aself.x)*i1; acc1.y = (acc1.y + e1*aself.y)*i1;
        acc1.z = (acc1.z + e1*aself.z)*i1; acc1.w = (acc1.w + e1*aself.w)*i1;
        acc2.x = (acc2.x + e2*aself.x)*i2; acc2.y = (acc2.y + e2*aself.y)*i2;
        acc2.z = (acc2.z + e2*aself.z)*i2; acc2.w = (acc2.w + e2*aself.w)*i2;
        acc3.x = (acc3.x + e3*aself.x)*i3; acc3.y = (acc3.y + e3*aself.y)*i3;
        acc3.z = (acc3.z + e3*aself.z)*i3; acc3.w = (acc3.w + e3*aself.w)*i3;
        float* ap = agg + (size_t)n*DH;
        *(float4*)(ap +  0 + f) = acc0;
        *(float4*)(ap + 32 + f) = acc1;
        *(float4*)(ap + 64 + f) = acc2;
        *(float4*)(ap + 96 + f) = acc3;
    }
}

// C3 = 0.25*agg@Wmix + b3, 32 rows/block, fused BN stats
__global__ __launch_bounds__(256) void k_w3mix(const float* __restrict__ agg,
        const float* __restrict__ W3, const float* __restrict__ b3,
        float* __restrict__ C, float* __restrict__ spart, int N){
    __shared__ float as_[32*132];
    __shared__ float wf[128*32];
    __shared__ float ob[32];
    int t = threadIdx.x;
    for (int i = t; i < 4096; i += 256){
        int kk = i >> 5, c = i & 31;
        int hh = kk >> 5, k = kk & 31;
        wf[i] = W3[k*DH + hh*HID_ + c];
    }
    if (t < 32) ob[t] = b3[t];
    int nbase = blockIdx.x*32;
    const float4* ag = (const float4*)(agg + (size_t)nbase*DH);
    for (int i = t; i < 32*32; i += 256){
        int row = i >> 5, col4 = i & 31;
        float4 v = (nbase + row < N) ? ag[i] : float4{0,0,0,0};
        *(float4*)&as_[row*132 + col4*4] = v;
    }
    __syncthreads();
    int rg = t >> 3;
    int cq = t & 7;
    int n = nbase + rg;
    float4 acc = {0,0,0,0};
    const float* xr = &as_[rg*132];
    const float4* wf4 = (const float4*)wf;
    #pragma unroll 8
    for (int k = 0; k < 128; k++){
        float xv = xr[k];
        float4 w = wf4[k*8 + cq];
        acc.x += xv*w.x; acc.y += xv*w.y; acc.z += xv*w.z; acc.w += xv*w.w;
    }
    float4 o = {0,0,0,0};
    if (n < N){
        o = float4{0.25f*acc.x + ob[cq*4], 0.25f*acc.y + ob[cq*4+1],
                   0.25f*acc.z + ob[cq*4+2], 0.25f*acc.w + ob[cq*4+3]};
        *(float4*)(C + (size_t)n*HID_ + cq*4) = o;
    }
    __syncthreads();
    *(float4*)&as_[rg*132 + cq*4] = o;
    __syncthreads();
    if (t < 32){
        float s = 0.f, s2 = 0.f;
        #pragma unroll 4
        for (int r = 0; r < 32; r++){
            float v = as_[r*132 + t];
            s += v; s2 += v*v;
        }
        spart[(size_t)blockIdx.x*64 + t]      = s;
        spart[(size_t)blockIdx.x*64 + 32 + t] = s2;
    }
}

// fused BN2-apply + layer-3 asrc/adst: A = elu(BN(C)), [asrc|adst] = A @ Wsd
__global__ void k_bnattn(const float* __restrict__ C, int N,
                         const float* __restrict__ stats, const float* __restrict__ g,
                         const float* __restrict__ be, float invN,
                         const float* __restrict__ Wsd,
                         float* __restrict__ A, float* __restrict__ asrc, float* __restrict__ adst){
    __shared__ float ws[256];
    __shared__ float scs[32], bos[32];
    int t = threadIdx.x;
    ws[t] = Wsd[t & 255];
    if (t < 32){
        float mu = stats[t]*invN;
        float var = stats[128+t]*invN - mu*mu;
        float sc = rsqrtf(var + 1e-5f)*g[t];
        scs[t] = sc; bos[t] = be[t] - mu*sc;
    }
    __syncthreads();
    int n = blockIdx.x*blockDim.x + t;
    if (n >= N) return;
    const float4* cr = (const float4*)(C + (size_t)n*HID_);
    float4* ar = (float4*)(A + (size_t)n*HID_);
    float s[8] = {0,0,0,0,0,0,0,0};
    #pragma unroll
    for (int kq = 0; kq < 8; kq++){
        float4 v = cr[kq];
        int f = kq*4;
        float4 a;
        a.x = elu_(v.x*scs[f]   + bos[f]);
        a.y = elu_(v.y*scs[f+1] + bos[f+1]);
        a.z = elu_(v.z*scs[f+2] + bos[f+2]);
        a.w = elu_(v.w*scs[f+3] + bos[f+3]);
        ar[kq] = a;
        const float* w0 = &ws[kq*32];
        #pragma unroll
        for (int r = 0; r < 8; r++)
            s[r] += a.x*w0[r] + a.y*w0[8+r] + a.z*w0[16+r] + a.w*w0[24+r];
    }
    *(float4*)(asrc + (size_t)n*4) = float4{s[0],s[1],s[2],s[3]};
    *(float4*)(adst + (size_t)n*4) = float4{s[4],s[5],s[6],s[7]};
}

// two-stage BN-partials reduction
__global__ void k_statsred1(const float* __restrict__ spart, int nb, int D,
                            float* __restrict__ spart2){
    int t = threadIdx.x;
    if (t >= 2*D) return;
    int K = (nb + gridDim.x - 1)/gridDim.x;
    int b0 = blockIdx.x*K;
    int b1 = min(nb, b0 + K);
    float a0=0.f, a1=0.f, a2=0.f, a3=0.f;
    int b = b0;
    for (; b + 4 <= b1; b += 4){
        a0 += spart[(size_t)b*2*D + t];
        a1 += spart[(size_t)(b+1)*2*D + t];
        a2 += spart[(size_t)(b+2)*2*D + t];
        a3 += spart[(size_t)(b+3)*2*D + t];
    }
    float s = (a0 + a1) + (a2 + a3);
    for (; b < b1; b++) s += spart[(size_t)b*2*D + t];
    spart2[(size_t)blockIdx.x*2*D + t] = s;
}

__global__ void k_statsred(const float* __restrict__ spart, int nb, int D,
                           float* __restrict__ stats){
    int t = threadIdx.x;
    if (t >= 2*D) return;
    float a0=0.f, a1=0.f, a2=0.f, a3=0.f;
    int b = 0;
    for (; b + 4 <= nb; b += 4){
        a0 += spart[(size_t)b*2*D + t];
        a1 += spart[(size_t)(b+1)*2*D + t];
        a2 += spart[(size_t)(b+2)*2*D + t];
        a3 += spart[(size_t)(b+3)*2*D + t];
    }
    float s = (a0 + a1) + (a2 + a3);
    for (; b < nb; b++) s += spart[(size_t)b*2*D + t];
    stats[t < D ? t : 128 + (t - D)] = s;
}

// pooling + fc, one block per graph, BN3+elu fused on load
__global__ __launch_bounds__(256) void k_poolfc(const float* __restrict__ C, int N,
        const float* __restrict__ stats, const float* __restrict__ g3, const float* __restrict__ be3,
        float invN,
        const float* __restrict__ gw, const float* __restrict__ gb,
        const int* __restrict__ batch, float* __restrict__ exg,
        const float* __restrict__ fcW, const float* __restrict__ fcb,
        float* __restrict__ out){
    int gId = blockIdx.x;
    int t = threadIdx.x;
    int lo = 0, hi = N;
    while (lo < hi){ int mid = (lo+hi) >> 1; if (batch[mid] < gId) lo = mid+1; else hi = mid; }
    int st = lo;
    hi = N;
    while (lo < hi){ int mid = (lo+hi) >> 1; if (batch[mid] < gId+1) lo = mid+1; else hi = mid; }
    int en = lo;

    __shared__ float gws[32];
    __shared__ float scs[32], bos[32];
    __shared__ float red[256];
    if (t < 32){
        gws[t] = gw[t];
        float mu = stats[t]*invN;
        float var = stats[128+t]*invN - mu*mu;
        float sc = rsqrtf(var + 1e-5f)*g3[t];
        scs[t] = sc; bos[t] = be3[t] - mu*sc;
    }
    __syncthreads();

    float den = 0.f;
    for (int n = st + t; n < en; n += 256){
        const float4* xr = (const float4*)(C + (size_t)n*HID_);
        float s = 0.f;
        #pragma unroll
        for (int q = 0; q < 8; q++){
            float4 v = xr[q];
            int f = q*4;
            s += elu_(v.x*scs[f]   + bos[f])  *gws[f]
               + elu_(v.y*scs[f+1] + bos[f+1])*gws[f+1]
               + elu_(v.z*scs[f+2] + bos[f+2])*gws[f+2]
               + elu_(v.w*scs[f+3] + bos[f+3])*gws[f+3];
        }
        float ex = __expf(s + gb[0]);
        exg[n] = ex;
        den += ex;
    }
    red[t] = den; __syncthreads();
    for (int off = 128; off > 0; off >>= 1){
        if (t < off) red[t] += red[t+off];
        __syncthreads();
    }
    float invd = 1.f/(red[0] + 1e-16f);
    __syncthreads();

    int c = t & 31, rg = t >> 5;
    float acc = 0.f;
    for (int n = st + rg; n < en; n += 8)
        acc += exg[n]*elu_(C[(size_t)n*HID_ + c]*scs[c] + bos[c]);
    red[t] = acc; __syncthreads();
    if (t < 128) red[t] += red[t+128];
    __syncthreads();
    if (t < 64) red[t] += red[t+64];
    __syncthreads();
    if (t < 32) red[t] += red[t+32];
    __syncthreads();
    if (t < 2){
        float s = 0.f;
        for (int cc = 0; cc < 32; cc++) s += red[cc]*invd*fcW[cc*2 + t];
        out[gId*2 + t] = s + fcb[t];
    }
}

extern "C" void kernel_launch(void* const* d_in, const int* in_sizes, int n_in,
                              void* d_out, int out_size, void* d_ws, size_t ws_size,
                              hipStream_t stream){
    const float* x   = (const float*)d_in[0];
    const int*   src = (const int*)d_in[1];
    const int*   dst = (const int*)d_in[2];
    const float* ea  = (const float*)d_in[3];
    const int* batch = (const int*)d_in[4];
    const float *W1=(const float*)d_in[5],  *as1=(const float*)d_in[6],  *ad1=(const float*)d_in[7];
    const float *We1=(const float*)d_in[8], *ae1=(const float*)d_in[9],  *b1=(const float*)d_in[10];
    const float *W2=(const float*)d_in[11], *as2=(const float*)d_in[12], *ad2=(const float*)d_in[13];
    const float *We2=(const float*)d_in[14],*ae2=(const float*)d_in[15], *b2=(const float*)d_in[16];
    const float *W3=(const float*)d_in[17], *as3=(const float*)d_in[18], *ad3=(const float*)d_in[19];
    const float *We3=(const float*)d_in[20],*ae3=(const float*)d_in[21], *b3=(const float*)d_in[22];
    const float *g1=(const float*)d_in[23], *be1=(const float*)d_in[24];
    const float *g2=(const float*)d_in[25], *be2=(const float*)d_in[26];
    const float *g3=(const float*)d_in[27], *be3=(const float*)d_in[28];
    const float *gw=(const float*)d_in[29], *gb=(const float*)d_in[30];
    const float *fcW=(const float*)d_in[31],*fcb=(const float*)d_in[32];
    int N = in_sizes[0]/DH;
    int E = in_sizes[1];
    float invN = 1.f/(float)N;

    const int tb = 256;
    int gE = (E + tb - 1)/tb;
    int nP = (gE > 1024) ? gE : 1024;
    int gL = (N + 15)/16;
    int gMix = (N + 31)/32;
    size_t spartN = (size_t)gL*256;
    const int RED1 = 64;

    float* ws = (float*)d_ws;
    size_t off = 0;
    float* A = ws + off;    off += (size_t)N*DH;
    float* B = ws + off;    off += (size_t)N*DH;
    float* C = ws + off;    off += (size_t)N*DH;
    float* asrc = ws + off; off += (size_t)N*4;
    float* adst = ws + off; off += (size_t)N*4;
    int* ints   = (int*)(ws + off);
    int* srcs   = ints;
    int* dsts   = ints + (size_t)E;
    int* perm   = ints + 2*(size_t)E;
    int* srcs2  = ints + 3*(size_t)E;
    int* perm2  = ints + 4*(size_t)E;
    int* rowst  = ints + 5*(size_t)E;
    int* counts = rowst + (N + 1);
    int* cursor = counts + N;
    int* bsums  = cursor + N;
    off += 5*(size_t)E + (N + 1) + 2*(size_t)N + 256;
    off = (off + 3) & ~(size_t)3;
    float* Ve     = ws + off;      // 192
    float* selfae = Ve + 192;      // 16
    float* stats  = selfae + 16;   // 3*256
    float* Wsd    = stats + 768;   // 256
    float* exg    = Wsd + 256;     // N
    float* partials = exg + N;     // nP*16
    float* spart  = partials + (size_t)nP*16;
    float* spart2 = spart + spartN;   // RED1*256
    off += 192 + 16 + 768 + 256 + (size_t)N + (size_t)nP*16 + spartN + (size_t)RED1*256;
    bool full = (off + (size_t)E*12)*sizeof(float) <= ws_size;
    float* ae0 = ws + off;
    float* ae1b = full ? ae0 + (size_t)E*4 : ae0;
    float* ae2b = full ? ae0 + (size_t)E*8 : ae0;

    hipMemsetAsync(counts, 0, (size_t)(2*N + 256)*sizeof(int), stream);

    int nb = (N + 511)/512;
    k_hist<<<gE, tb, 0, stream>>>(dst, E, counts);
    k_scan1<<<nb, 512, 0, stream>>>(counts, N, rowst, bsums);
    k_scan2<<<1, 1, 0, stream>>>(bsums, nb);
    k_scan3<<<(N + tb - 1)/tb, tb, 0, stream>>>(rowst, bsums, N, E);
    k_setup<<<1, 256, 0, stream>>>(We1, ae1, We2, ae2, We3, ae3, Ve, W3, as3, ad3, Wsd);
    k_scatter<<<gE, tb, 0, stream>>>(src, dst, E, rowst, cursor, srcs, dsts, perm);
    k_rank<<<gE, tb, 0, stream>>>(srcs, dsts, perm, rowst, E, srcs2, perm2);
    if (full){
        k_aedge3<<<gE, tb, 0, stream>>>(ea, perm2, E, Ve, ae0, ae1b, ae2b, partials);
        k_colfin<<<1, 256, 0, stream>>>(partials, gE, Ve, 1.f/(float)E, selfae);
    } else {
        k_eamean<<<1024, 256, 0, stream>>>(ea, E, partials);
        k_colfin<<<1, 256, 0, stream>>>(partials, 1024, Ve, 1.f/(float)E, selfae);
    }

    int gG = (N + 63)/64;
    // layer 1 (concat)
    k_gemm128<0><<<gG, 256, 0, stream>>>(x, W1, as1, ad1, stats, g1, be1, invN, B, asrc, adst, N);
    if (!full) k_aedge1<<<gE, tb, 0, stream>>>(ea, perm2, E, Ve, 0, ae0);
    k_aggL<1><<<gL, 256, 0, stream>>>(rowst, srcs2, asrc, adst, ae0, B, selfae + 0, b1, C, spart, N);
    k_statsred1<<<RED1, 256, 0, stream>>>(spart, gL, DH, spart2);
    k_statsred<<<1, 256, 0, stream>>>(spart2, RED1, DH, stats);
    // layer 2 (mean); BN1+elu fused into gemm input
    k_gemm128<1><<<gG, 256, 0, stream>>>(C, W2, as2, ad2, stats, g1, be1, invN, B, asrc, adst, N);
    if (!full) k_aedge1<<<gE, tb, 0, stream>>>(ea, perm2, E, Ve, 1, ae1b);
    k_aggL<0><<<gL, 256, 0, stream>>>(rowst, srcs2, asrc, adst, ae1b, B, selfae + 4, b2, C, spart, N);
    k_statsred1<<<RED1, 256, 0, stream>>>(spart, gL, HID_, spart2);
    k_statsred<<<1, 256, 0, stream>>>(spart2, RED1, HID_, stats + 256);
    // layer 3: fused BN2-apply + attn (one pass), then A-space aggregation + W3 GEMM
    k_bnattn<<<(N + tb - 1)/tb, tb, 0, stream>>>(C, N, stats + 256, g2, be2, invN, Wsd, A, asrc, adst);
    if (!full) k_aedge1<<<gE, tb, 0, stream>>>(ea, perm2, E, Ve, 2, ae2b);
    k_aggA<<<(N + 31)/32, 256, 0, stream>>>(rowst, srcs2, asrc, adst, ae2b, A, selfae + 8, B, N);
    k_w3mix<<<gMix, 256, 0, stream>>>(B, W3, b3, C, spart, N);
    k_statsred1<<<RED1, 256, 0, stream>>>(spart, gMix, HID_, spart2);
    k_statsred<<<1, 256, 0, stream>>>(spart2, RED1, HID_, stats + 512);
    // pooling + fc (BN3 fused)
    k_poolfc<<<NG_, 256, 0, stream>>>(C, N, stats + 512, g3, be3, invN, gw, gb, batch, exg, fcW, fcb, (float*)d_out);
}